// Round 2
// baseline (1000.192 us; speedup 1.0000x reference)
//
#include <hip/hip_runtime.h>

// ChebGCN: x -> relu(lin1) -> relu(cheb1) -> relu(cheb2) -> lin2 -> softmax
// N=100000 nodes, E=1600000 edges, IN=256, HID=128, EMB1=64, EMB2=32, K=3

constexpr int IN_DIM = 256;
constexpr int HID    = 128;
constexpr int EMB1   = 64;
constexpr int EMB2   = 32;

// ---------------- degree / norm / CSR build ----------------

__global__ void count_kernel(const int* __restrict__ src, const int* __restrict__ dst,
                             int E, int* __restrict__ cnt_src, int* __restrict__ cnt_dst) {
    int e = blockIdx.x * blockDim.x + threadIdx.x;
    if (e < E) {
        atomicAdd(&cnt_src[src[e]], 1);
        atomicAdd(&cnt_dst[dst[e]], 1);
    }
}

__global__ void dinv_kernel(const int* __restrict__ cnt_src, float* __restrict__ dinv, int N) {
    int n = blockIdx.x * blockDim.x + threadIdx.x;
    if (n < N) {
        int c = cnt_src[n];
        dinv[n] = (c > 0) ? rsqrtf((float)c) : 0.f;
    }
}

__global__ void scan_part(const int* __restrict__ cnt, int N, int* __restrict__ partial) {
    __shared__ int s[256];
    int tid = threadIdx.x;
    int i = blockIdx.x * 256 + tid;
    s[tid] = (i < N) ? cnt[i] : 0;
    __syncthreads();
    for (int st = 128; st > 0; st >>= 1) {
        if (tid < st) s[tid] += s[tid + st];
        __syncthreads();
    }
    if (tid == 0) partial[blockIdx.x] = s[0];
}

// one block, 512 threads: exclusive scan of P (<512) partials in place
__global__ void scan_mid(int* __restrict__ partial, int P) {
    __shared__ int s[512];
    int tid = threadIdx.x;
    int v = (tid < P) ? partial[tid] : 0;
    s[tid] = v;
    __syncthreads();
    for (int off = 1; off < 512; off <<= 1) {
        int t = (tid >= off) ? s[tid - off] : 0;
        __syncthreads();
        s[tid] += t;
        __syncthreads();
    }
    if (tid < P) partial[tid] = s[tid] - v;   // exclusive
}

__global__ void scan_final(const int* __restrict__ cnt, const int* __restrict__ partial,
                           int* __restrict__ row_ptr, int N) {
    __shared__ int s[256];
    int tid = threadIdx.x;
    int i = blockIdx.x * 256 + tid;
    int v = (i < N) ? cnt[i] : 0;
    s[tid] = v;
    __syncthreads();
    for (int off = 1; off < 256; off <<= 1) {
        int t = (tid >= off) ? s[tid - off] : 0;
        __syncthreads();
        s[tid] += t;
        __syncthreads();
    }
    if (i < N) row_ptr[i] = partial[blockIdx.x] + s[tid] - v;   // exclusive
    if (i == N - 1) row_ptr[N] = partial[blockIdx.x] + s[tid];  // total = E
}

__global__ void scatter_kernel(const int* __restrict__ src, const int* __restrict__ dst,
                               const float* __restrict__ dinv, const int* __restrict__ row_ptr,
                               int* __restrict__ fill, int* __restrict__ esrc,
                               float* __restrict__ enorm, int E) {
    int e = blockIdx.x * blockDim.x + threadIdx.x;
    if (e < E) {
        int s = src[e], d = dst[e];
        int pos = row_ptr[d] + atomicAdd(&fill[d], 1);
        esrc[pos] = s;
        enorm[pos] = -dinv[s] * dinv[d];
    }
}

// Weff: rows[0:H)=W0-W2, rows[H:2H)=W1, rows[2H:3H)=2*W2  (each H x Eo, row-major)
__global__ void weff_kernel(const float* __restrict__ W, int H, int Eo, float* __restrict__ Weff) {
    int i = blockIdx.x * blockDim.x + threadIdx.x;
    int sz = H * Eo;
    if (i < sz) {
        float w0 = W[i];
        float w1 = W[sz + i];
        float w2 = W[2 * sz + i];
        Weff[i]          = w0 - w2;
        Weff[sz + i]     = w1;
        Weff[2 * sz + i] = 2.f * w2;
    }
}

// ---------------- GEMM: C[N x BN] = relu([A0|A1|A2][N x K] @ B[K x BN] + bias) ----------------
// BM=64 rows/block, BK=16; 256 threads: tx=tid&15 (col group, TN=BN/16 cols), ty=tid>>4 (4 rows)

template <int BN>
__global__ __launch_bounds__(256) void gemm_kernel(
    const float* __restrict__ A0, const float* __restrict__ A1, const float* __restrict__ A2,
    int H, int K, int Nrows,
    const float* __restrict__ B, const float* __restrict__ bias,
    float* __restrict__ C, int do_relu) {
    constexpr int BM = 64, BK = 16;
    constexpr int TN = BN / 16;   // 8 / 4 / 2
    constexpr int APAD = 68;      // 16B-aligned row stride, decorrelates banks

    __shared__ float As[BK][APAD];  // transposed: As[k][row]
    __shared__ float Bs[BK][BN];

    const int tid = threadIdx.x;
    const int tx = tid & 15;
    const int ty = tid >> 4;
    const int row0 = blockIdx.x * BM;

    float acc[4][TN];
#pragma unroll
    for (int m = 0; m < 4; m++)
#pragma unroll
        for (int n = 0; n < TN; n++) acc[m][n] = 0.f;

    const int arow = tid >> 2;        // 0..63
    const int kq = (tid & 3) * 4;     // 0,4,8,12
    const int grow_a = row0 + arow;

    for (int k0 = 0; k0 < K; k0 += BK) {
        const float* Ab;
        int kloc;
        if (k0 < H)          { Ab = A0; kloc = k0; }
        else if (k0 < 2 * H) { Ab = A1; kloc = k0 - H; }
        else                 { Ab = A2; kloc = k0 - 2 * H; }

        float4 av = make_float4(0.f, 0.f, 0.f, 0.f);
        if (grow_a < Nrows)
            av = *reinterpret_cast<const float4*>(&Ab[(size_t)grow_a * H + kloc + kq]);

        __syncthreads();
        As[kq + 0][arow] = av.x;
        As[kq + 1][arow] = av.y;
        As[kq + 2][arow] = av.z;
        As[kq + 3][arow] = av.w;

        if constexpr (BN == 128) {
#pragma unroll
            for (int i = 0; i < 2; i++) {
                int lin = i * 1024 + tid * 4;
                int bk = lin >> 7, bc = lin & 127;
                *reinterpret_cast<float4*>(&Bs[bk][bc]) =
                    *reinterpret_cast<const float4*>(&B[(size_t)(k0 + bk) * BN + bc]);
            }
        } else if constexpr (BN == 64) {
            int lin = tid * 4;
            int bk = lin >> 6, bc = lin & 63;
            *reinterpret_cast<float4*>(&Bs[bk][bc]) =
                *reinterpret_cast<const float4*>(&B[(size_t)(k0 + bk) * BN + bc]);
        } else {  // 32
            int lin = tid * 2;
            int bk = lin >> 5, bc = lin & 31;
            *reinterpret_cast<float2*>(&Bs[bk][bc]) =
                *reinterpret_cast<const float2*>(&B[(size_t)(k0 + bk) * BN + bc]);
        }
        __syncthreads();

#pragma unroll
        for (int kk = 0; kk < BK; ++kk) {
            float4 a = *reinterpret_cast<const float4*>(&As[kk][ty * 4]);
            float bv[TN];
            if constexpr (TN == 8) {
                float4 b0 = *reinterpret_cast<const float4*>(&Bs[kk][tx * 8]);
                float4 b1 = *reinterpret_cast<const float4*>(&Bs[kk][tx * 8 + 4]);
                bv[0] = b0.x; bv[1] = b0.y; bv[2] = b0.z; bv[3] = b0.w;
                bv[4] = b1.x; bv[5] = b1.y; bv[6] = b1.z; bv[7] = b1.w;
            } else if constexpr (TN == 4) {
                float4 b0 = *reinterpret_cast<const float4*>(&Bs[kk][tx * 4]);
                bv[0] = b0.x; bv[1] = b0.y; bv[2] = b0.z; bv[3] = b0.w;
            } else {
                float2 b0 = *reinterpret_cast<const float2*>(&Bs[kk][tx * 2]);
                bv[0] = b0.x; bv[1] = b0.y;
            }
#pragma unroll
            for (int n = 0; n < TN; n++) {
                acc[0][n] += a.x * bv[n];
                acc[1][n] += a.y * bv[n];
                acc[2][n] += a.z * bv[n];
                acc[3][n] += a.w * bv[n];
            }
        }
    }

#pragma unroll
    for (int m = 0; m < 4; m++) {
        int grow = row0 + ty * 4 + m;
        if (grow >= Nrows) continue;
#pragma unroll
        for (int n = 0; n < TN; n++) {
            float v = acc[m][n] + bias[tx * TN + n];
            if (do_relu) v = fmaxf(v, 0.f);
            C[(size_t)grow * BN + tx * TN + n] = v;
        }
    }
}

// ---------------- propagation: out[d][:] = sum_{e in CSR[d]} h[esrc[e]][:] * enorm[e] ----------

template <int F>
__global__ __launch_bounds__(256) void prop_kernel(
    const float* __restrict__ h, const int* __restrict__ row_ptr,
    const int* __restrict__ esrc, const float* __restrict__ enorm,
    float* __restrict__ out, int Nn) {
    int node = blockIdx.x * 4 + (threadIdx.x >> 6);
    int lane = threadIdx.x & 63;
    if (node >= Nn) return;
    int beg = row_ptr[node];
    int end = row_ptr[node + 1];

    if constexpr (F == 128) {
        float ax = 0.f, ay = 0.f;
        int i = beg;
        for (; i + 1 < end; i += 2) {
            int s0 = esrc[i], s1 = esrc[i + 1];
            float w0 = enorm[i], w1 = enorm[i + 1];
            float2 v0 = *reinterpret_cast<const float2*>(&h[(size_t)s0 * 128 + lane * 2]);
            float2 v1 = *reinterpret_cast<const float2*>(&h[(size_t)s1 * 128 + lane * 2]);
            ax += v0.x * w0 + v1.x * w1;
            ay += v0.y * w0 + v1.y * w1;
        }
        if (i < end) {
            int s0 = esrc[i];
            float w0 = enorm[i];
            float2 v0 = *reinterpret_cast<const float2*>(&h[(size_t)s0 * 128 + lane * 2]);
            ax += v0.x * w0;
            ay += v0.y * w0;
        }
        float2 r = make_float2(ax, ay);
        *reinterpret_cast<float2*>(&out[(size_t)node * 128 + lane * 2]) = r;
    } else {  // F == 64
        float acc = 0.f;
        int i = beg;
        for (; i + 1 < end; i += 2) {
            int s0 = esrc[i], s1 = esrc[i + 1];
            float w0 = enorm[i], w1 = enorm[i + 1];
            acc += h[(size_t)s0 * 64 + lane] * w0 + h[(size_t)s1 * 64 + lane] * w1;
        }
        if (i < end) acc += h[(size_t)esrc[i] * 64 + lane] * enorm[i];
        out[(size_t)node * 64 + lane] = acc;
    }
}

// ---------------- head: logits = h2 @ W_lin2 + b; softmax over 2 classes ----------------

__global__ void head_kernel(const float* __restrict__ h2, const float* __restrict__ W,
                            const float* __restrict__ b, float* __restrict__ out, int N) {
    int n = blockIdx.x * blockDim.x + threadIdx.x;
    if (n < N) {
        float l0 = b[0], l1 = b[1];
        const float4* hp = reinterpret_cast<const float4*>(h2 + (size_t)n * 32);
#pragma unroll
        for (int q = 0; q < 8; q++) {
            float4 v = hp[q];
            int j = q * 4;
            l0 += v.x * W[(j + 0) * 2] + v.y * W[(j + 1) * 2] + v.z * W[(j + 2) * 2] + v.w * W[(j + 3) * 2];
            l1 += v.x * W[(j + 0) * 2 + 1] + v.y * W[(j + 1) * 2 + 1] + v.z * W[(j + 2) * 2 + 1] + v.w * W[(j + 3) * 2 + 1];
        }
        float m = fmaxf(l0, l1);
        float e0 = expf(l0 - m), e1 = expf(l1 - m);
        float s = e0 + e1;
        out[(size_t)n * 2 + 0] = e0 / s;
        out[(size_t)n * 2 + 1] = e1 / s;
    }
}

// ---------------- launch ----------------

extern "C" void kernel_launch(void* const* d_in, const int* in_sizes, int n_in,
                              void* d_out, int out_size, void* d_ws, size_t ws_size,
                              hipStream_t stream) {
    const float* x       = (const float*)d_in[0];
    const int*   eidx    = (const int*)d_in[1];
    const float* W_lin1  = (const float*)d_in[2];
    const float* b_lin1  = (const float*)d_in[3];
    const float* W_cheb1 = (const float*)d_in[4];
    const float* b_cheb1 = (const float*)d_in[5];
    const float* W_cheb2 = (const float*)d_in[6];
    const float* b_cheb2 = (const float*)d_in[7];
    const float* W_lin2  = (const float*)d_in[8];
    const float* b_lin2  = (const float*)d_in[9];
    float* out = (float*)d_out;

    const int N = in_sizes[0] / IN_DIM;
    const int E = in_sizes[1] / 2;
    const int* src = eidx;
    const int* dst = eidx + E;

    float* fws = (float*)d_ws;
    size_t o = 0;
    float* h0    = fws + o; o += (size_t)N * HID;
    float* P1    = fws + o; o += (size_t)N * HID;
    float* P2    = fws + o; o += (size_t)N * HID;
    float* h1    = fws + o; o += (size_t)N * EMB1;
    float* dinv  = fws + o; o += N;
    float* enorm = fws + o; o += E;
    float* Weff1 = fws + o; o += 3 * HID * EMB1;
    float* Weff2 = fws + o; o += 3 * EMB1 * EMB2;
    int* cnt_src = (int*)(fws + o); o += N;
    int* cnt_dst = (int*)(fws + o); o += N;
    int* row_ptr = (int*)(fws + o); o += (N + 1);
    int* fill    = (int*)(fws + o); o += N;
    int* partial = (int*)(fws + o); o += 1024;
    int* esrc    = (int*)(fws + o); o += E;

    // buffer reuse for layer 2 (safe: producers/consumers are stream-ordered)
    float* Q1 = h0;   // prop(h1)
    float* Q2 = P1;   // prop(Q1)
    float* h2 = P2;   // gemm3 out (reads h1,Q1,Q2 only)

    hipMemsetAsync(cnt_src, 0, (size_t)N * 4, stream);
    hipMemsetAsync(cnt_dst, 0, (size_t)N * 4, stream);
    hipMemsetAsync(fill,    0, (size_t)N * 4, stream);

    const int tb = 256;
    count_kernel<<<(E + tb - 1) / tb, tb, 0, stream>>>(src, dst, E, cnt_src, cnt_dst);
    dinv_kernel<<<(N + tb - 1) / tb, tb, 0, stream>>>(cnt_src, dinv, N);

    const int P = (N + 255) / 256;   // 391 <= 512
    scan_part<<<P, 256, 0, stream>>>(cnt_dst, N, partial);
    scan_mid<<<1, 512, 0, stream>>>(partial, P);
    scan_final<<<P, 256, 0, stream>>>(cnt_dst, partial, row_ptr, N);
    scatter_kernel<<<(E + tb - 1) / tb, tb, 0, stream>>>(src, dst, dinv, row_ptr, fill, esrc, enorm, E);

    weff_kernel<<<(HID * EMB1 + tb - 1) / tb, tb, 0, stream>>>(W_cheb1, HID, EMB1, Weff1);
    weff_kernel<<<(EMB1 * EMB2 + tb - 1) / tb, tb, 0, stream>>>(W_cheb2, EMB1, EMB2, Weff2);

    const int ggrid = (N + 63) / 64;
    gemm_kernel<HID><<<ggrid, 256, 0, stream>>>(x, nullptr, nullptr, IN_DIM, IN_DIM, N,
                                                W_lin1, b_lin1, h0, 1);
    prop_kernel<HID><<<(N + 3) / 4, 256, 0, stream>>>(h0, row_ptr, esrc, enorm, P1, N);
    prop_kernel<HID><<<(N + 3) / 4, 256, 0, stream>>>(P1, row_ptr, esrc, enorm, P2, N);
    gemm_kernel<EMB1><<<ggrid, 256, 0, stream>>>(h0, P1, P2, HID, 3 * HID, N,
                                                 Weff1, b_cheb1, h1, 1);
    prop_kernel<EMB1><<<(N + 3) / 4, 256, 0, stream>>>(h1, row_ptr, esrc, enorm, Q1, N);
    prop_kernel<EMB1><<<(N + 3) / 4, 256, 0, stream>>>(Q1, row_ptr, esrc, enorm, Q2, N);
    gemm_kernel<EMB2><<<ggrid, 256, 0, stream>>>(h1, Q1, Q2, EMB1, 3 * EMB1, N,
                                                 Weff2, b_cheb2, h2, 1);
    head_kernel<<<(N + tb - 1) / tb, tb, 0, stream>>>(h2, W_lin2, b_lin2, out, N);
}

// Round 3
// 833.575 us; speedup vs baseline: 1.1999x; 1.1999x over previous
//
#include <hip/hip_runtime.h>

// ChebGCN: x -> relu(lin1) -> relu(cheb1) -> relu(cheb2) -> lin2 -> softmax
// N=100000 nodes, E=1600000 edges, IN=256, HID=128, EMB1=64, EMB2=32, K=3
// Round 3: bucket-sort CSR build (no mass global atomics), bf16 activations.

constexpr int IN_DIM = 256;
constexpr int HID    = 128;
constexpr int EMB1   = 64;
constexpr int EMB2   = 32;

__device__ __forceinline__ float bf2f(unsigned short u) {
    return __uint_as_float((unsigned)u << 16);
}
__device__ __forceinline__ unsigned short f2bf(float f) {
    unsigned u = __float_as_uint(f);
    u += 0x7fffu + ((u >> 16) & 1u);   // round-to-nearest-even
    return (unsigned short)(u >> 16);
}

// ---------------- CSR build: two-level bucket sort by dst ----------------
// bucket = dst >> 10 (1024 nodes per bucket, nb = ceil(N/1024) = 98 <= 128)
// packed edge: bits 0..16 = src (N < 2^17), bits 17..26 = dst & 1023

__global__ __launch_bounds__(256) void bucket_hist(const int* __restrict__ dst, int E,
                                                   unsigned* __restrict__ bucket_cnt /*nb*16, padded*/) {
    __shared__ unsigned h[128];
    for (int i = threadIdx.x; i < 128; i += 256) h[i] = 0;
    __syncthreads();
    int i0 = blockIdx.x * 4096;
#pragma unroll
    for (int j = 0; j < 16; j++) {
        int i = i0 + j * 256 + threadIdx.x;
        if (i < E) atomicAdd(&h[dst[i] >> 10], 1u);
    }
    __syncthreads();
    for (int i = threadIdx.x; i < 128; i += 256)
        if (h[i]) atomicAdd(&bucket_cnt[i * 16], h[i]);
}

// single block, 128 threads: scan nb bucket counts; init bases/fills; row_ptr[N]=E
__global__ void bucket_scan(const unsigned* __restrict__ bucket_cnt, int nb,
                            unsigned* __restrict__ bucket_base, unsigned* __restrict__ bucket_fill,
                            int* __restrict__ row_ptr, int N, int E) {
    __shared__ unsigned s[128];
    int t = threadIdx.x;
    unsigned v = (t < nb) ? bucket_cnt[t * 16] : 0;
    s[t] = v;
    __syncthreads();
    for (int off = 1; off < 128; off <<= 1) {
        unsigned u = (t >= off) ? s[t - off] : 0;
        __syncthreads();
        s[t] += u;
        __syncthreads();
    }
    if (t < nb) {
        unsigned excl = s[t] - v;
        bucket_base[t] = excl;
        bucket_fill[t * 16] = excl;
    }
    if (t == nb) bucket_base[nb] = (unsigned)E;
    if (t == 0) row_ptr[N] = E;
}

__global__ __launch_bounds__(256) void bucket_scatter(const int* __restrict__ src,
                                                      const int* __restrict__ dst, int E,
                                                      unsigned* __restrict__ bucket_fill,
                                                      unsigned* __restrict__ tmp) {
    __shared__ unsigned h[128];
    __shared__ unsigned base[128];
    for (int i = threadIdx.x; i < 128; i += 256) h[i] = 0;
    __syncthreads();
    int i0 = blockIdx.x * 4096;
    unsigned pk[16], bk[16];
#pragma unroll
    for (int j = 0; j < 16; j++) {
        int i = i0 + j * 256 + threadIdx.x;
        if (i < E) {
            int sv = src[i], dv = dst[i];
            bk[j] = (unsigned)(dv >> 10);
            pk[j] = (unsigned)sv | ((unsigned)(dv & 1023) << 17);
            atomicAdd(&h[bk[j]], 1u);
        } else {
            bk[j] = 0xffffffffu;
        }
    }
    __syncthreads();
    for (int i = threadIdx.x; i < 128; i += 256)
        base[i] = h[i] ? atomicAdd(&bucket_fill[i * 16], h[i]) : 0u;
    __syncthreads();
    for (int i = threadIdx.x; i < 128; i += 256) h[i] = 0;
    __syncthreads();
#pragma unroll
    for (int j = 0; j < 16; j++) {
        if (bk[j] != 0xffffffffu) {
            unsigned r = atomicAdd(&h[bk[j]], 1u);
            tmp[base[bk[j]] + r] = pk[j];
        }
    }
}

// src-degree via partial LDS histograms: R ranges of 16384 nodes x C=16 chunks, no atomics on merge
__global__ __launch_bounds__(256) void deg_count(const int* __restrict__ src, int E, int N,
                                                 unsigned* __restrict__ partial) {
    __shared__ unsigned h[16384];   // 64 KB
    int r = blockIdx.x >> 4, c = blockIdx.x & 15;
    for (int i = threadIdx.x; i < 16384; i += 256) h[i] = 0;
    __syncthreads();
    int lo = r << 14;
    int per = (E + 15) / 16;
    int b0 = c * per, b1 = min(b0 + per, E);
    for (int i = b0 + threadIdx.x; i < b1; i += 256) {
        int s = src[i] - lo;
        if ((unsigned)s < 16384u) atomicAdd(&h[s], 1u);
    }
    __syncthreads();
    unsigned* out = partial + ((size_t)blockIdx.x << 14);
    for (int i = threadIdx.x; i < 16384; i += 256) out[i] = h[i];
}

__global__ void deg_reduce(const unsigned* __restrict__ partial, float* __restrict__ dinv, int N) {
    int n = blockIdx.x * 256 + threadIdx.x;
    if (n >= N) return;
    int r = n >> 14, idx = n & 16383;
    const unsigned* p = partial + (((size_t)r * 16) << 14) + idx;
    unsigned d = 0;
#pragma unroll
    for (int c = 0; c < 16; c++) d += p[(size_t)c << 14];
    dinv[n] = d ? rsqrtf((float)d) : 0.f;
}

// per-bucket: count 1024 local dsts, scan -> row_ptr, place edges, compute enorm
__global__ __launch_bounds__(512) void bucket_sort(const unsigned* __restrict__ tmp,
                                                   const unsigned* __restrict__ bucket_base,
                                                   const float* __restrict__ dinv,
                                                   int* __restrict__ row_ptr,
                                                   int* __restrict__ esrc, float* __restrict__ enorm,
                                                   int N) {
    __shared__ unsigned lcnt[1024];
    __shared__ unsigned lfill[1024];
    __shared__ float    ldinv[1024];
    __shared__ unsigned ssum[512];
    int b = blockIdx.x;
    unsigned beg = bucket_base[b], end = bucket_base[b + 1];
    int node0 = b << 10;
    int t = threadIdx.x;

    lcnt[t] = 0; lcnt[t + 512] = 0;
    ldinv[t]       = (node0 + t < N)       ? dinv[node0 + t]       : 0.f;
    ldinv[t + 512] = (node0 + t + 512 < N) ? dinv[node0 + t + 512] : 0.f;
    __syncthreads();

    for (unsigned i = beg + t; i < end; i += 512)
        atomicAdd(&lcnt[(tmp[i] >> 17) & 1023], 1u);
    __syncthreads();

    unsigned v0 = lcnt[2 * t], v1 = lcnt[2 * t + 1];
    unsigned sp = v0 + v1;
    ssum[t] = sp;
    __syncthreads();
    for (int off = 1; off < 512; off <<= 1) {
        unsigned u = (t >= off) ? ssum[t - off] : 0;
        __syncthreads();
        ssum[t] += u;
        __syncthreads();
    }
    unsigned exclp = ssum[t] - sp;
    unsigned e0 = beg + exclp, e1 = beg + exclp + v0;
    lfill[2 * t] = e0;
    lfill[2 * t + 1] = e1;
    if (node0 + 2 * t < N)     row_ptr[node0 + 2 * t] = (int)e0;
    if (node0 + 2 * t + 1 < N) row_ptr[node0 + 2 * t + 1] = (int)e1;
    __syncthreads();

    for (unsigned i = beg + t; i < end; i += 512) {
        unsigned pkv = tmp[i];
        unsigned sN = pkv & 0x1ffffu;
        unsigned dl = (pkv >> 17) & 1023u;
        unsigned pos = atomicAdd(&lfill[dl], 1u);
        esrc[pos] = (int)sN;
        enorm[pos] = -dinv[sN] * ldinv[dl];
    }
}

// Weff: rows[0:H)=W0-W2, rows[H:2H)=W1, rows[2H:3H)=2*W2  (each H x Eo, row-major)
__global__ void weff_kernel(const float* __restrict__ W, int H, int Eo, float* __restrict__ Weff) {
    int i = blockIdx.x * blockDim.x + threadIdx.x;
    int sz = H * Eo;
    if (i < sz) {
        float w0 = W[i];
        float w1 = W[sz + i];
        float w2 = W[2 * sz + i];
        Weff[i]          = w0 - w2;
        Weff[sz + i]     = w1;
        Weff[2 * sz + i] = 2.f * w2;
    }
}

// ---------------- GEMM: C[N x BN](bf16) = relu([A0|A1|A2][N x K] @ B[K x BN] + bias) ----------
// A dtype: fp32 (AF32=true, for x) or bf16. B/bias fp32 in LDS path.

template <int BN, bool AF32>
__global__ __launch_bounds__(256) void gemm_kernel(
    const void* __restrict__ A0v, const void* __restrict__ A1v, const void* __restrict__ A2v,
    int H, int K, int Nrows,
    const float* __restrict__ B, const float* __restrict__ bias,
    unsigned short* __restrict__ C, int do_relu) {
    constexpr int BM = 64, BK = 16;
    constexpr int TN = BN / 16;   // 8 / 4 / 2
    constexpr int APAD = 68;

    __shared__ float As[BK][APAD];
    __shared__ float Bs[BK][BN];

    const int tid = threadIdx.x;
    const int tx = tid & 15;
    const int ty = tid >> 4;
    const int row0 = blockIdx.x * BM;

    float acc[4][TN];
#pragma unroll
    for (int m = 0; m < 4; m++)
#pragma unroll
        for (int n = 0; n < TN; n++) acc[m][n] = 0.f;

    const int arow = tid >> 2;
    const int kq = (tid & 3) * 4;
    const int grow_a = row0 + arow;

    for (int k0 = 0; k0 < K; k0 += BK) {
        const void* Ab;
        int kloc;
        if (k0 < H)          { Ab = A0v; kloc = k0; }
        else if (k0 < 2 * H) { Ab = A1v; kloc = k0 - H; }
        else                 { Ab = A2v; kloc = k0 - 2 * H; }

        float4 av = make_float4(0.f, 0.f, 0.f, 0.f);
        if (grow_a < Nrows) {
            if constexpr (AF32) {
                av = *reinterpret_cast<const float4*>((const float*)Ab + (size_t)grow_a * H + kloc + kq);
            } else {
                ushort4 u = *reinterpret_cast<const ushort4*>((const unsigned short*)Ab +
                                                              (size_t)grow_a * H + kloc + kq);
                av = make_float4(bf2f(u.x), bf2f(u.y), bf2f(u.z), bf2f(u.w));
            }
        }

        __syncthreads();
        As[kq + 0][arow] = av.x;
        As[kq + 1][arow] = av.y;
        As[kq + 2][arow] = av.z;
        As[kq + 3][arow] = av.w;

        if constexpr (BN == 128) {
#pragma unroll
            for (int i = 0; i < 2; i++) {
                int lin = i * 1024 + tid * 4;
                int bk = lin >> 7, bc = lin & 127;
                *reinterpret_cast<float4*>(&Bs[bk][bc]) =
                    *reinterpret_cast<const float4*>(&B[(size_t)(k0 + bk) * BN + bc]);
            }
        } else if constexpr (BN == 64) {
            int lin = tid * 4;
            int bk = lin >> 6, bc = lin & 63;
            *reinterpret_cast<float4*>(&Bs[bk][bc]) =
                *reinterpret_cast<const float4*>(&B[(size_t)(k0 + bk) * BN + bc]);
        } else {
            int lin = tid * 2;
            int bk = lin >> 5, bc = lin & 31;
            *reinterpret_cast<float2*>(&Bs[bk][bc]) =
                *reinterpret_cast<const float2*>(&B[(size_t)(k0 + bk) * BN + bc]);
        }
        __syncthreads();

#pragma unroll
        for (int kk = 0; kk < BK; ++kk) {
            float4 a = *reinterpret_cast<const float4*>(&As[kk][ty * 4]);
            float bv[TN];
            if constexpr (TN == 8) {
                float4 b0 = *reinterpret_cast<const float4*>(&Bs[kk][tx * 8]);
                float4 b1 = *reinterpret_cast<const float4*>(&Bs[kk][tx * 8 + 4]);
                bv[0] = b0.x; bv[1] = b0.y; bv[2] = b0.z; bv[3] = b0.w;
                bv[4] = b1.x; bv[5] = b1.y; bv[6] = b1.z; bv[7] = b1.w;
            } else if constexpr (TN == 4) {
                float4 b0 = *reinterpret_cast<const float4*>(&Bs[kk][tx * 4]);
                bv[0] = b0.x; bv[1] = b0.y; bv[2] = b0.z; bv[3] = b0.w;
            } else {
                float2 b0 = *reinterpret_cast<const float2*>(&Bs[kk][tx * 2]);
                bv[0] = b0.x; bv[1] = b0.y;
            }
#pragma unroll
            for (int n = 0; n < TN; n++) {
                acc[0][n] += a.x * bv[n];
                acc[1][n] += a.y * bv[n];
                acc[2][n] += a.z * bv[n];
                acc[3][n] += a.w * bv[n];
            }
        }
    }

#pragma unroll
    for (int m = 0; m < 4; m++) {
        int grow = row0 + ty * 4 + m;
        if (grow >= Nrows) continue;
#pragma unroll
        for (int n = 0; n < TN; n++) {
            float v = acc[m][n] + bias[tx * TN + n];
            if (do_relu) v = fmaxf(v, 0.f);
            C[(size_t)grow * BN + tx * TN + n] = f2bf(v);
        }
    }
}

// ---------------- propagation (bf16 in/out, fp32 accumulate) ----------------

template <int F>
__global__ __launch_bounds__(256) void prop_kernel(
    const unsigned short* __restrict__ h, const int* __restrict__ row_ptr,
    const int* __restrict__ esrc, const float* __restrict__ enorm,
    unsigned short* __restrict__ out, int Nn) {
    constexpr int LANES = F / 2;        // 64 (F=128) or 32 (F=64)
    constexpr int NPB = 256 / LANES;    // nodes per block
    int node = blockIdx.x * NPB + threadIdx.x / LANES;
    int l = (threadIdx.x % LANES) * 2;  // feature index (pair)
    if (node >= Nn) return;
    int beg = row_ptr[node];
    int end = row_ptr[node + 1];

    float ax = 0.f, ay = 0.f;
    int i = beg;
    for (; i + 1 < end; i += 2) {
        int s0 = esrc[i], s1 = esrc[i + 1];
        float w0 = enorm[i], w1 = enorm[i + 1];
        unsigned u0 = *reinterpret_cast<const unsigned*>(&h[(size_t)s0 * F + l]);
        unsigned u1 = *reinterpret_cast<const unsigned*>(&h[(size_t)s1 * F + l]);
        ax += __uint_as_float(u0 << 16) * w0;
        ay += __uint_as_float(u0 & 0xffff0000u) * w0;
        ax += __uint_as_float(u1 << 16) * w1;
        ay += __uint_as_float(u1 & 0xffff0000u) * w1;
    }
    if (i < end) {
        int s0 = esrc[i];
        float w0 = enorm[i];
        unsigned u0 = *reinterpret_cast<const unsigned*>(&h[(size_t)s0 * F + l]);
        ax += __uint_as_float(u0 << 16) * w0;
        ay += __uint_as_float(u0 & 0xffff0000u) * w0;
    }
    unsigned o = (unsigned)f2bf(ax) | ((unsigned)f2bf(ay) << 16);
    *reinterpret_cast<unsigned*>(&out[(size_t)node * F + l]) = o;
}

// ---------------- head: logits = h2(bf16) @ W_lin2 + b; softmax(2) ----------------

__global__ void head_kernel(const unsigned short* __restrict__ h2, const float* __restrict__ W,
                            const float* __restrict__ b, float* __restrict__ out, int N) {
    int n = blockIdx.x * blockDim.x + threadIdx.x;
    if (n >= N) return;
    float l0 = b[0], l1 = b[1];
    const unsigned* hp = reinterpret_cast<const unsigned*>(h2 + (size_t)n * 32);
#pragma unroll
    for (int q = 0; q < 16; q++) {
        unsigned u = hp[q];
        float f0 = __uint_as_float(u << 16);
        float f1 = __uint_as_float(u & 0xffff0000u);
        l0 += f0 * W[(2 * q) * 2]     + f1 * W[(2 * q + 1) * 2];
        l1 += f0 * W[(2 * q) * 2 + 1] + f1 * W[(2 * q + 1) * 2 + 1];
    }
    float m = fmaxf(l0, l1);
    float e0 = expf(l0 - m), e1 = expf(l1 - m);
    float s = e0 + e1;
    out[(size_t)n * 2 + 0] = e0 / s;
    out[(size_t)n * 2 + 1] = e1 / s;
}

// ---------------- launch ----------------

extern "C" void kernel_launch(void* const* d_in, const int* in_sizes, int n_in,
                              void* d_out, int out_size, void* d_ws, size_t ws_size,
                              hipStream_t stream) {
    const float* x       = (const float*)d_in[0];
    const int*   eidx    = (const int*)d_in[1];
    const float* W_lin1  = (const float*)d_in[2];
    const float* b_lin1  = (const float*)d_in[3];
    const float* W_cheb1 = (const float*)d_in[4];
    const float* b_cheb1 = (const float*)d_in[5];
    const float* W_cheb2 = (const float*)d_in[6];
    const float* b_cheb2 = (const float*)d_in[7];
    const float* W_lin2  = (const float*)d_in[8];
    const float* b_lin2  = (const float*)d_in[9];
    float* out = (float*)d_out;

    const int N = in_sizes[0] / IN_DIM;
    const int E = in_sizes[1] / 2;
    const int* src = eidx;
    const int* dst = eidx + E;
    const int nb = (N + 1023) >> 10;          // 98
    const int R  = (N + 16383) >> 14;         // 7

    char* base = (char*)d_ws;
    auto alloc = [&](size_t bytes) -> char* {
        char* p = base;
        base += (bytes + 255) & ~(size_t)255;
        return p;
    };
    unsigned short* h0 = (unsigned short*)alloc((size_t)N * HID * 2);
    unsigned short* P1 = (unsigned short*)alloc((size_t)N * HID * 2);
    unsigned short* P2 = (unsigned short*)alloc((size_t)N * HID * 2);
    unsigned short* h1 = (unsigned short*)alloc((size_t)N * EMB1 * 2);
    float* dinv  = (float*)alloc((size_t)N * 4);
    float* enorm = (float*)alloc((size_t)E * 4);
    int*   esrc  = (int*)alloc((size_t)E * 4);
    unsigned* tmp     = (unsigned*)alloc((size_t)E * 4);
    unsigned* partial = (unsigned*)alloc((size_t)R * 16 * 16384 * 4);
    int* row_ptr      = (int*)alloc((size_t)(N + 1) * 4);
    unsigned* bucket_cnt  = (unsigned*)alloc(128 * 16 * 4);
    unsigned* bucket_base = (unsigned*)alloc(129 * 4);
    unsigned* bucket_fill = (unsigned*)alloc(128 * 16 * 4);
    float* Weff1 = (float*)alloc((size_t)3 * HID * EMB1 * 4);
    float* Weff2 = (float*)alloc((size_t)3 * EMB1 * EMB2 * 4);

    // layer-2 buffer reuse (stream-ordered)
    unsigned short* Q1 = h0;
    unsigned short* Q2 = P1;
    unsigned short* h2 = P2;

    hipMemsetAsync(bucket_cnt, 0, 128 * 16 * 4, stream);

    const int EB = (E + 4095) / 4096;         // 391
    bucket_hist<<<EB, 256, 0, stream>>>(dst, E, bucket_cnt);
    bucket_scan<<<1, 128, 0, stream>>>(bucket_cnt, nb, bucket_base, bucket_fill, row_ptr, N, E);
    bucket_scatter<<<EB, 256, 0, stream>>>(src, dst, E, bucket_fill, tmp);
    deg_count<<<R * 16, 256, 0, stream>>>(src, E, N, partial);
    deg_reduce<<<(N + 255) / 256, 256, 0, stream>>>(partial, dinv, N);
    bucket_sort<<<nb, 512, 0, stream>>>(tmp, bucket_base, dinv, row_ptr, esrc, enorm, N);

    const int tb = 256;
    weff_kernel<<<(HID * EMB1 + tb - 1) / tb, tb, 0, stream>>>(W_cheb1, HID, EMB1, Weff1);
    weff_kernel<<<(EMB1 * EMB2 + tb - 1) / tb, tb, 0, stream>>>(W_cheb2, EMB1, EMB2, Weff2);

    const int ggrid = (N + 63) / 64;
    gemm_kernel<HID, true><<<ggrid, 256, 0, stream>>>(x, nullptr, nullptr, IN_DIM, IN_DIM, N,
                                                      W_lin1, b_lin1, h0, 1);
    prop_kernel<HID><<<(N + 1) / 2, 256, 0, stream>>>(h0, row_ptr, esrc, enorm, P1, N);
    prop_kernel<HID><<<(N + 1) / 2, 256, 0, stream>>>(P1, row_ptr, esrc, enorm, P2, N);
    gemm_kernel<EMB1, false><<<ggrid, 256, 0, stream>>>(h0, P1, P2, HID, 3 * HID, N,
                                                        Weff1, b_cheb1, h1, 1);
    prop_kernel<EMB1><<<(N + 7) / 8, 256, 0, stream>>>(h1, row_ptr, esrc, enorm, Q1, N);
    prop_kernel<EMB1><<<(N + 7) / 8, 256, 0, stream>>>(Q1, row_ptr, esrc, enorm, Q2, N);
    gemm_kernel<EMB2, false><<<ggrid, 256, 0, stream>>>(h1, Q1, Q2, EMB1, 3 * EMB1, N,
                                                        Weff2, b_cheb2, h2, 1);
    head_kernel<<<(N + tb - 1) / tb, tb, 0, stream>>>(h2, W_lin2, b_lin2, out, N);
}

// Round 4
// 684.392 us; speedup vs baseline: 1.4614x; 1.2180x over previous
//
#include <hip/hip_runtime.h>

// ChebGCN: x -> relu(lin1) -> relu(cheb1) -> relu(cheb2) -> lin2 -> softmax
// N=100000, E=1600000, IN=256, HID=128, EMB1=64, EMB2=32, K=3
// Round 4: high-occupancy degree histogram; bf16 MFMA GEMMs.

constexpr int IN_DIM = 256;
constexpr int HID    = 128;
constexpr int EMB1   = 64;
constexpr int EMB2   = 32;

typedef __attribute__((ext_vector_type(8))) short bf16x8;
typedef __attribute__((ext_vector_type(4))) float f32x4;

__device__ __forceinline__ unsigned short f2bf(float f) {
    unsigned u = __float_as_uint(f);
    u += 0x7fffu + ((u >> 16) & 1u);   // RNE
    return (unsigned short)(u >> 16);
}

// ---------------- CSR build: two-level bucket sort by dst ----------------

__global__ __launch_bounds__(256) void bucket_hist(const int* __restrict__ dst, int E,
                                                   unsigned* __restrict__ bucket_cnt) {
    __shared__ unsigned h[128];
    for (int i = threadIdx.x; i < 128; i += 256) h[i] = 0;
    __syncthreads();
    int i0 = blockIdx.x * 4096;
#pragma unroll
    for (int j = 0; j < 16; j++) {
        int i = i0 + j * 256 + threadIdx.x;
        if (i < E) atomicAdd(&h[dst[i] >> 10], 1u);
    }
    __syncthreads();
    for (int i = threadIdx.x; i < 128; i += 256)
        if (h[i]) atomicAdd(&bucket_cnt[i * 16], h[i]);
}

__global__ void bucket_scan(const unsigned* __restrict__ bucket_cnt, int nb,
                            unsigned* __restrict__ bucket_base, unsigned* __restrict__ bucket_fill,
                            int* __restrict__ row_ptr, int N, int E) {
    __shared__ unsigned s[128];
    int t = threadIdx.x;
    unsigned v = (t < nb) ? bucket_cnt[t * 16] : 0;
    s[t] = v;
    __syncthreads();
    for (int off = 1; off < 128; off <<= 1) {
        unsigned u = (t >= off) ? s[t - off] : 0;
        __syncthreads();
        s[t] += u;
        __syncthreads();
    }
    if (t < nb) {
        unsigned excl = s[t] - v;
        bucket_base[t] = excl;
        bucket_fill[t * 16] = excl;
    }
    if (t == nb) bucket_base[nb] = (unsigned)E;
    if (t == 0) row_ptr[N] = E;
}

__global__ __launch_bounds__(256) void bucket_scatter(const int* __restrict__ src,
                                                      const int* __restrict__ dst, int E,
                                                      unsigned* __restrict__ bucket_fill,
                                                      unsigned* __restrict__ tmp) {
    __shared__ unsigned h[128];
    __shared__ unsigned base[128];
    for (int i = threadIdx.x; i < 128; i += 256) h[i] = 0;
    __syncthreads();
    int i0 = blockIdx.x * 4096;
    unsigned pk[16], bk[16];
#pragma unroll
    for (int j = 0; j < 16; j++) {
        int i = i0 + j * 256 + threadIdx.x;
        if (i < E) {
            int sv = src[i], dv = dst[i];
            bk[j] = (unsigned)(dv >> 10);
            pk[j] = (unsigned)sv | ((unsigned)(dv & 1023) << 17);
            atomicAdd(&h[bk[j]], 1u);
        } else {
            bk[j] = 0xffffffffu;
        }
    }
    __syncthreads();
    for (int i = threadIdx.x; i < 128; i += 256)
        base[i] = h[i] ? atomicAdd(&bucket_fill[i * 16], h[i]) : 0u;
    __syncthreads();
    for (int i = threadIdx.x; i < 128; i += 256) h[i] = 0;
    __syncthreads();
#pragma unroll
    for (int j = 0; j < 16; j++) {
        if (bk[j] != 0xffffffffu) {
            unsigned r = atomicAdd(&h[bk[j]], 1u);
            tmp[base[bk[j]] + r] = pk[j];
        }
    }
}

// src out-degree: R ranges x C=128 chunks; 16384 counters packed 2-per-u32 (32KB LDS)
__global__ __launch_bounds__(256) void deg_count(const int* __restrict__ src, int E,
                                                 unsigned* __restrict__ partial) {
    __shared__ unsigned h[8192];
    int r = blockIdx.x >> 7, c = blockIdx.x & 127;
    for (int i = threadIdx.x; i < 8192; i += 256) h[i] = 0;
    __syncthreads();
    int lo = r << 14;
    int per = (E + 127) >> 7;
    int b0 = c * per, b1 = min(b0 + per, E);
    for (int i = b0 + threadIdx.x; i < b1; i += 256) {
        int s = src[i] - lo;
        if ((unsigned)s < 16384u)
            atomicAdd(&h[s >> 1], (s & 1) ? 0x10000u : 1u);
    }
    __syncthreads();
    unsigned* out = partial + ((size_t)blockIdx.x << 13);
    for (int i = threadIdx.x; i < 8192; i += 256) out[i] = h[i];
}

__global__ void deg_reduce(const unsigned* __restrict__ partial, float* __restrict__ dinv, int N) {
    int n = blockIdx.x * 256 + threadIdx.x;
    if (n >= N) return;
    int r = n >> 14, word = (n & 16383) >> 1;
    const unsigned* p = partial + (((size_t)r * 128) << 13) + word;
    unsigned d = 0;
#pragma unroll
    for (int c = 0; c < 128; c++) d += p[(size_t)c << 13];
    d = (n & 1) ? (d >> 16) : (d & 0xffffu);
    dinv[n] = d ? rsqrtf((float)d) : 0.f;
}

// per-bucket: count 1024 local dsts, scan -> row_ptr, place edges, compute enorm
__global__ __launch_bounds__(512) void bucket_sort(const unsigned* __restrict__ tmp,
                                                   const unsigned* __restrict__ bucket_base,
                                                   const float* __restrict__ dinv,
                                                   int* __restrict__ row_ptr,
                                                   int* __restrict__ esrc, float* __restrict__ enorm,
                                                   int N) {
    __shared__ unsigned lcnt[1024];
    __shared__ unsigned lfill[1024];
    __shared__ float    ldinv[1024];
    __shared__ unsigned ssum[512];
    int b = blockIdx.x;
    unsigned beg = bucket_base[b], end = bucket_base[b + 1];
    int node0 = b << 10;
    int t = threadIdx.x;

    lcnt[t] = 0; lcnt[t + 512] = 0;
    ldinv[t]       = (node0 + t < N)       ? dinv[node0 + t]       : 0.f;
    ldinv[t + 512] = (node0 + t + 512 < N) ? dinv[node0 + t + 512] : 0.f;
    __syncthreads();

    for (unsigned i = beg + t; i < end; i += 512)
        atomicAdd(&lcnt[(tmp[i] >> 17) & 1023], 1u);
    __syncthreads();

    unsigned v0 = lcnt[2 * t], v1 = lcnt[2 * t + 1];
    unsigned sp = v0 + v1;
    ssum[t] = sp;
    __syncthreads();
    for (int off = 1; off < 512; off <<= 1) {
        unsigned u = (t >= off) ? ssum[t - off] : 0;
        __syncthreads();
        ssum[t] += u;
        __syncthreads();
    }
    unsigned exclp = ssum[t] - sp;
    unsigned e0 = beg + exclp, e1 = beg + exclp + v0;
    lfill[2 * t] = e0;
    lfill[2 * t + 1] = e1;
    if (node0 + 2 * t < N)     row_ptr[node0 + 2 * t] = (int)e0;
    if (node0 + 2 * t + 1 < N) row_ptr[node0 + 2 * t + 1] = (int)e1;
    __syncthreads();

    for (unsigned i = beg + t; i < end; i += 512) {
        unsigned pkv = tmp[i];
        unsigned sN = pkv & 0x1ffffu;
        unsigned dl = (pkv >> 17) & 1023u;
        unsigned pos = atomicAdd(&lfill[dl], 1u);
        esrc[pos] = (int)sN;
        enorm[pos] = -dinv[sN] * ldinv[dl];
    }
}

// Weff: rows[0:H)=W0-W2, rows[H:2H)=W1, rows[2H:3H)=2*W2
__global__ void weff_kernel(const float* __restrict__ W, int H, int Eo, float* __restrict__ Weff) {
    int i = blockIdx.x * blockDim.x + threadIdx.x;
    int sz = H * Eo;
    if (i < sz) {
        float w0 = W[i];
        float w1 = W[sz + i];
        float w2 = W[2 * sz + i];
        Weff[i]          = w0 - w2;
        Weff[sz + i]     = w1;
        Weff[2 * sz + i] = 2.f * w2;
    }
}

// ---------------- MFMA GEMM: C[N x BN](bf16) = relu([A0|A1|A2] @ B + bias) ----------------
// 256 threads = 4 waves; block = 64 rows; wave w owns rows w*16..w*16+15, all BN cols.
// B staged in LDS transposed [n][k] bf16, XOR-swizzled 16B k-blocks (kblk ^= n&7).
// A staged per 32-k step into As[64][56] (112B stride: 16B-aligned, ~2-way banks = free).

template <int BN, int KTOT, int H, bool AF32>
__global__ __launch_bounds__(256) void mfma_gemm(
    const void* __restrict__ A0v, const void* __restrict__ A1v, const void* __restrict__ A2v,
    int Nrows, const float* __restrict__ B, const float* __restrict__ bias,
    unsigned short* __restrict__ C, int do_relu)
{
    constexpr int KSTEPS = KTOT / 32;
    constexpr int NT = BN / 16;
    constexpr int SPM = H / 32;   // k-steps per A sub-matrix

    __shared__ unsigned short Bs[BN][KTOT];
    __shared__ unsigned short As[64][56];

    const int tid = threadIdx.x;
    const int w = tid >> 6;
    const int l = tid & 63;
    const int lr = l & 15;
    const int g  = l >> 4;
    const int row0 = blockIdx.x * 64;

    // ---- stage B (once): read fp32 [k][n], convert, write transposed+swizzled ----
    for (int idx = tid; idx < (KTOT / 2) * BN; idx += 256) {
        int n = idx % BN, kp = idx / BN, k = kp * 2;
        float w0 = B[(size_t)k * BN + n];
        float w1 = B[(size_t)(k + 1) * BN + n];
        unsigned pk = (unsigned)f2bf(w0) | ((unsigned)f2bf(w1) << 16);
        int sw = (k >> 3) ^ (n & 7);
        *reinterpret_cast<unsigned*>(&Bs[n][sw * 8 + (k & 7)]) = pk;
    }

    float biasv[NT];
#pragma unroll
    for (int t = 0; t < NT; t++) biasv[t] = bias[t * 16 + lr];

    f32x4 acc[NT];
#pragma unroll
    for (int t = 0; t < NT; t++) acc[t] = (f32x4){0.f, 0.f, 0.f, 0.f};

    // ---- A staging: thread covers row=tid>>2, 8 k at q=tid&3 ----
    const int arow = tid >> 2;
    const int aq = tid & 3;
    const int grow_a = row0 + arow;
    uint4 areg;

    auto loadA = [&](int ks) {
        int m = ks / SPM;
        int kloc = (ks % SPM) * 32 + aq * 8;
        const void* Ap = (m == 0) ? A0v : (m == 1) ? A1v : A2v;
        uint4 v = make_uint4(0u, 0u, 0u, 0u);
        if (grow_a < Nrows) {
            if constexpr (AF32) {
                const float* p = (const float*)Ap + (size_t)grow_a * H + kloc;
                float4 a0 = *reinterpret_cast<const float4*>(p);
                float4 a1 = *reinterpret_cast<const float4*>(p + 4);
                v.x = (unsigned)f2bf(a0.x) | ((unsigned)f2bf(a0.y) << 16);
                v.y = (unsigned)f2bf(a0.z) | ((unsigned)f2bf(a0.w) << 16);
                v.z = (unsigned)f2bf(a1.x) | ((unsigned)f2bf(a1.y) << 16);
                v.w = (unsigned)f2bf(a1.z) | ((unsigned)f2bf(a1.w) << 16);
            } else {
                v = *reinterpret_cast<const uint4*>((const unsigned short*)Ap +
                                                    (size_t)grow_a * H + kloc);
            }
        }
        areg = v;
    };

    loadA(0);
    __syncthreads();   // B staged

    for (int ks = 0; ks < KSTEPS; ks++) {
        *reinterpret_cast<uint4*>(&As[arow][aq * 8]) = areg;
        __syncthreads();
        if (ks + 1 < KSTEPS) loadA(ks + 1);   // prefetch; lands before next As write

        bf16x8 af = *reinterpret_cast<const bf16x8*>(&As[w * 16 + lr][g * 8]);
#pragma unroll
        for (int t = 0; t < NT; t++) {
            int n = t * 16 + lr;
            int sw = ((ks * 4 + g) ^ (lr & 7));
            bf16x8 bf = *reinterpret_cast<const bf16x8*>(&Bs[n][sw * 8]);
            acc[t] = __builtin_amdgcn_mfma_f32_16x16x32_bf16(af, bf, acc[t], 0, 0, 0);
        }
        __syncthreads();
    }

    // ---- store: D row=(l>>4)*4+reg, col=lane&15 (HW-verified mapping) ----
#pragma unroll
    for (int t = 0; t < NT; t++) {
#pragma unroll
        for (int r = 0; r < 4; r++) {
            int grow = row0 + w * 16 + g * 4 + r;
            if (grow < Nrows) {
                float v = acc[t][r] + biasv[t];
                if (do_relu) v = fmaxf(v, 0.f);
                C[(size_t)grow * BN + t * 16 + lr] = f2bf(v);
            }
        }
    }
}

// ---------------- propagation (bf16 in/out, fp32 accumulate) ----------------

template <int F>
__global__ __launch_bounds__(256) void prop_kernel(
    const unsigned short* __restrict__ h, const int* __restrict__ row_ptr,
    const int* __restrict__ esrc, const float* __restrict__ enorm,
    unsigned short* __restrict__ out, int Nn) {
    constexpr int LANES = F / 2;
    constexpr int NPB = 256 / LANES;
    int node = blockIdx.x * NPB + threadIdx.x / LANES;
    int l = (threadIdx.x % LANES) * 2;
    if (node >= Nn) return;
    int beg = row_ptr[node];
    int end = row_ptr[node + 1];

    float ax = 0.f, ay = 0.f;
    int i = beg;
    for (; i + 1 < end; i += 2) {
        int s0 = esrc[i], s1 = esrc[i + 1];
        float w0 = enorm[i], w1 = enorm[i + 1];
        unsigned u0 = *reinterpret_cast<const unsigned*>(&h[(size_t)s0 * F + l]);
        unsigned u1 = *reinterpret_cast<const unsigned*>(&h[(size_t)s1 * F + l]);
        ax += __uint_as_float(u0 << 16) * w0;
        ay += __uint_as_float(u0 & 0xffff0000u) * w0;
        ax += __uint_as_float(u1 << 16) * w1;
        ay += __uint_as_float(u1 & 0xffff0000u) * w1;
    }
    if (i < end) {
        int s0 = esrc[i];
        float w0 = enorm[i];
        unsigned u0 = *reinterpret_cast<const unsigned*>(&h[(size_t)s0 * F + l]);
        ax += __uint_as_float(u0 << 16) * w0;
        ay += __uint_as_float(u0 & 0xffff0000u) * w0;
    }
    unsigned o = (unsigned)f2bf(ax) | ((unsigned)f2bf(ay) << 16);
    *reinterpret_cast<unsigned*>(&out[(size_t)node * F + l]) = o;
}

// ---------------- head ----------------

__global__ void head_kernel(const unsigned short* __restrict__ h2, const float* __restrict__ W,
                            const float* __restrict__ b, float* __restrict__ out, int N) {
    int n = blockIdx.x * blockDim.x + threadIdx.x;
    if (n >= N) return;
    float l0 = b[0], l1 = b[1];
    const unsigned* hp = reinterpret_cast<const unsigned*>(h2 + (size_t)n * 32);
#pragma unroll
    for (int q = 0; q < 16; q++) {
        unsigned u = hp[q];
        float f0 = __uint_as_float(u << 16);
        float f1 = __uint_as_float(u & 0xffff0000u);
        l0 += f0 * W[(2 * q) * 2]     + f1 * W[(2 * q + 1) * 2];
        l1 += f0 * W[(2 * q) * 2 + 1] + f1 * W[(2 * q + 1) * 2 + 1];
    }
    float m = fmaxf(l0, l1);
    float e0 = expf(l0 - m), e1 = expf(l1 - m);
    float s = e0 + e1;
    out[(size_t)n * 2 + 0] = e0 / s;
    out[(size_t)n * 2 + 1] = e1 / s;
}

// ---------------- launch ----------------

extern "C" void kernel_launch(void* const* d_in, const int* in_sizes, int n_in,
                              void* d_out, int out_size, void* d_ws, size_t ws_size,
                              hipStream_t stream) {
    const float* x       = (const float*)d_in[0];
    const int*   eidx    = (const int*)d_in[1];
    const float* W_lin1  = (const float*)d_in[2];
    const float* b_lin1  = (const float*)d_in[3];
    const float* W_cheb1 = (const float*)d_in[4];
    const float* b_cheb1 = (const float*)d_in[5];
    const float* W_cheb2 = (const float*)d_in[6];
    const float* b_cheb2 = (const float*)d_in[7];
    const float* W_lin2  = (const float*)d_in[8];
    const float* b_lin2  = (const float*)d_in[9];
    float* out = (float*)d_out;

    const int N = in_sizes[0] / IN_DIM;
    const int E = in_sizes[1] / 2;
    const int* src = eidx;
    const int* dst = eidx + E;
    const int nb = (N + 1023) >> 10;          // 98
    const int R  = (N + 16383) >> 14;         // 7

    char* base = (char*)d_ws;
    auto alloc = [&](size_t bytes) -> char* {
        char* p = base;
        base += (bytes + 255) & ~(size_t)255;
        return p;
    };
    unsigned short* h0 = (unsigned short*)alloc((size_t)N * HID * 2);
    unsigned short* P1 = (unsigned short*)alloc((size_t)N * HID * 2);
    unsigned short* P2 = (unsigned short*)alloc((size_t)N * HID * 2);
    unsigned short* h1 = (unsigned short*)alloc((size_t)N * EMB1 * 2);
    float* dinv  = (float*)alloc((size_t)N * 4);
    float* enorm = (float*)alloc((size_t)E * 4);
    int*   esrc  = (int*)alloc((size_t)E * 4);
    unsigned* tmp     = (unsigned*)alloc((size_t)E * 4);
    unsigned* partial = (unsigned*)alloc((size_t)R * 128 * 8192 * 4);
    int* row_ptr      = (int*)alloc((size_t)(N + 1) * 4);
    unsigned* bucket_cnt  = (unsigned*)alloc(128 * 16 * 4);
    unsigned* bucket_base = (unsigned*)alloc(129 * 4);
    unsigned* bucket_fill = (unsigned*)alloc(128 * 16 * 4);
    float* Weff1 = (float*)alloc((size_t)3 * HID * EMB1 * 4);
    float* Weff2 = (float*)alloc((size_t)3 * EMB1 * EMB2 * 4);

    unsigned short* Q1 = h0;
    unsigned short* Q2 = P1;
    unsigned short* h2 = P2;

    hipMemsetAsync(bucket_cnt, 0, 128 * 16 * 4, stream);

    const int EB = (E + 4095) / 4096;         // 391
    bucket_hist<<<EB, 256, 0, stream>>>(dst, E, bucket_cnt);
    bucket_scan<<<1, 128, 0, stream>>>(bucket_cnt, nb, bucket_base, bucket_fill, row_ptr, N, E);
    bucket_scatter<<<EB, 256, 0, stream>>>(src, dst, E, bucket_fill, tmp);
    deg_count<<<R * 128, 256, 0, stream>>>(src, E, partial);
    deg_reduce<<<(N + 255) / 256, 256, 0, stream>>>(partial, dinv, N);
    bucket_sort<<<nb, 512, 0, stream>>>(tmp, bucket_base, dinv, row_ptr, esrc, enorm, N);

    const int tb = 256;
    weff_kernel<<<(HID * EMB1 + tb - 1) / tb, tb, 0, stream>>>(W_cheb1, HID, EMB1, Weff1);
    weff_kernel<<<(EMB1 * EMB2 + tb - 1) / tb, tb, 0, stream>>>(W_cheb2, EMB1, EMB2, Weff2);

    const int ggrid = (N + 63) / 64;
    mfma_gemm<HID, IN_DIM, IN_DIM, true><<<ggrid, 256, 0, stream>>>(
        x, nullptr, nullptr, N, W_lin1, b_lin1, h0, 1);
    prop_kernel<HID><<<(N + 1) / 2, 256, 0, stream>>>(h0, row_ptr, esrc, enorm, P1, N);
    prop_kernel<HID><<<(N + 1) / 2, 256, 0, stream>>>(P1, row_ptr, esrc, enorm, P2, N);
    mfma_gemm<EMB1, 3 * HID, HID, false><<<ggrid, 256, 0, stream>>>(
        h0, P1, P2, N, Weff1, b_cheb1, h1, 1);
    prop_kernel<EMB1><<<(N + 7) / 8, 256, 0, stream>>>(h1, row_ptr, esrc, enorm, Q1, N);
    prop_kernel<EMB1><<<(N + 7) / 8, 256, 0, stream>>>(Q1, row_ptr, esrc, enorm, Q2, N);
    mfma_gemm<EMB2, 3 * EMB1, EMB1, false><<<ggrid, 256, 0, stream>>>(
        h1, Q1, Q2, N, Weff2, b_cheb2, h2, 1);
    head_kernel<<<(N + tb - 1) / tb, tb, 0, stream>>>(h2, W_lin2, b_lin2, out, N);
}

// Round 5
// 605.715 us; speedup vs baseline: 1.6513x; 1.1299x over previous
//
#include <hip/hip_runtime.h>

// ChebGCN: x -> relu(lin1) -> relu(cheb1) -> relu(cheb2) -> lin2 -> softmax
// N=100000, E=1600000, IN=256, HID=128, EMB1=64, EMB2=32, K=3
// Round 5: project-then-propagate (S commutes with W): per layer
//   out = h@(W0-W2) + S(h@W1 + S(h@2W2)),  props run at OUTPUT width.
// One-node-per-wave prop with edge-slots; packed (src,norm); fused head.

constexpr int IN_DIM = 256;
constexpr int HID    = 128;
constexpr int EMB1   = 64;
constexpr int EMB2   = 32;

typedef __attribute__((ext_vector_type(8))) short bf16x8;
typedef __attribute__((ext_vector_type(4))) float f32x4;

__device__ __forceinline__ float bf2f(unsigned short u) {
    return __uint_as_float((unsigned)u << 16);
}
__device__ __forceinline__ unsigned short f2bf(float f) {
    unsigned u = __float_as_uint(f);
    u += 0x7fffu + ((u >> 16) & 1u);   // RNE
    return (unsigned short)(u >> 16);
}

// ---------------- CSR build: two-level bucket sort by dst ----------------

__global__ __launch_bounds__(256) void bucket_hist(const int* __restrict__ dst, int E,
                                                   unsigned* __restrict__ bucket_cnt) {
    __shared__ unsigned h[128];
    for (int i = threadIdx.x; i < 128; i += 256) h[i] = 0;
    __syncthreads();
    int i0 = blockIdx.x * 4096;
#pragma unroll
    for (int j = 0; j < 16; j++) {
        int i = i0 + j * 256 + threadIdx.x;
        if (i < E) atomicAdd(&h[dst[i] >> 10], 1u);
    }
    __syncthreads();
    for (int i = threadIdx.x; i < 128; i += 256)
        if (h[i]) atomicAdd(&bucket_cnt[i * 16], h[i]);
}

__global__ void bucket_scan(const unsigned* __restrict__ bucket_cnt, int nb,
                            unsigned* __restrict__ bucket_base, unsigned* __restrict__ bucket_fill,
                            int* __restrict__ row_ptr, int N, int E) {
    __shared__ unsigned s[128];
    int t = threadIdx.x;
    unsigned v = (t < nb) ? bucket_cnt[t * 16] : 0;
    s[t] = v;
    __syncthreads();
    for (int off = 1; off < 128; off <<= 1) {
        unsigned u = (t >= off) ? s[t - off] : 0;
        __syncthreads();
        s[t] += u;
        __syncthreads();
    }
    if (t < nb) {
        unsigned excl = s[t] - v;
        bucket_base[t] = excl;
        bucket_fill[t * 16] = excl;
    }
    if (t == nb) bucket_base[nb] = (unsigned)E;
    if (t == 0) row_ptr[N] = E;
}

__global__ __launch_bounds__(256) void bucket_scatter(const int* __restrict__ src,
                                                      const int* __restrict__ dst, int E,
                                                      unsigned* __restrict__ bucket_fill,
                                                      unsigned* __restrict__ tmp) {
    __shared__ unsigned h[128];
    __shared__ unsigned base[128];
    for (int i = threadIdx.x; i < 128; i += 256) h[i] = 0;
    __syncthreads();
    int i0 = blockIdx.x * 4096;
    unsigned pk[16], bk[16];
#pragma unroll
    for (int j = 0; j < 16; j++) {
        int i = i0 + j * 256 + threadIdx.x;
        if (i < E) {
            int sv = src[i], dv = dst[i];
            bk[j] = (unsigned)(dv >> 10);
            pk[j] = (unsigned)sv | ((unsigned)(dv & 1023) << 17);
            atomicAdd(&h[bk[j]], 1u);
        } else {
            bk[j] = 0xffffffffu;
        }
    }
    __syncthreads();
    for (int i = threadIdx.x; i < 128; i += 256)
        base[i] = h[i] ? atomicAdd(&bucket_fill[i * 16], h[i]) : 0u;
    __syncthreads();
    for (int i = threadIdx.x; i < 128; i += 256) h[i] = 0;
    __syncthreads();
#pragma unroll
    for (int j = 0; j < 16; j++) {
        if (bk[j] != 0xffffffffu) {
            unsigned r = atomicAdd(&h[bk[j]], 1u);
            tmp[base[bk[j]] + r] = pk[j];
        }
    }
}

// src out-degree: R ranges x C=128 chunks; 16384 counters packed 2-per-u32 (32KB LDS)
__global__ __launch_bounds__(256) void deg_count(const int* __restrict__ src, int E,
                                                 unsigned* __restrict__ partial) {
    __shared__ unsigned h[8192];
    int r = blockIdx.x >> 7, c = blockIdx.x & 127;
    for (int i = threadIdx.x; i < 8192; i += 256) h[i] = 0;
    __syncthreads();
    int lo = r << 14;
    int per = (E + 127) >> 7;
    int b0 = c * per, b1 = min(b0 + per, E);
    for (int i = b0 + threadIdx.x; i < b1; i += 256) {
        int s = src[i] - lo;
        if ((unsigned)s < 16384u)
            atomicAdd(&h[s >> 1], (s & 1) ? 0x10000u : 1u);
    }
    __syncthreads();
    unsigned* out = partial + ((size_t)blockIdx.x << 13);
    for (int i = threadIdx.x; i < 8192; i += 256) out[i] = h[i];
}

__global__ void deg_reduce(const unsigned* __restrict__ partial, float* __restrict__ dinv, int N) {
    int n = blockIdx.x * 256 + threadIdx.x;
    if (n >= N) return;
    int r = n >> 14, word = (n & 16383) >> 1;
    const unsigned* p = partial + (((size_t)r * 128) << 13) + word;
    unsigned d = 0;
#pragma unroll
    for (int c = 0; c < 128; c++) d += p[(size_t)c << 13];
    d = (n & 1) ? (d >> 16) : (d & 0xffffu);
    dinv[n] = d ? rsqrtf((float)d) : 0.f;
}

// per-bucket: count 1024 local dsts, scan -> row_ptr, place edges as (src, norm)
__global__ __launch_bounds__(512) void bucket_sort(const unsigned* __restrict__ tmp,
                                                   const unsigned* __restrict__ bucket_base,
                                                   const float* __restrict__ dinv,
                                                   int* __restrict__ row_ptr,
                                                   uint2* __restrict__ epack, int N) {
    __shared__ unsigned lcnt[1024];
    __shared__ unsigned lfill[1024];
    __shared__ float    ldinv[1024];
    __shared__ unsigned ssum[512];
    int b = blockIdx.x;
    unsigned beg = bucket_base[b], end = bucket_base[b + 1];
    int node0 = b << 10;
    int t = threadIdx.x;

    lcnt[t] = 0; lcnt[t + 512] = 0;
    ldinv[t]       = (node0 + t < N)       ? dinv[node0 + t]       : 0.f;
    ldinv[t + 512] = (node0 + t + 512 < N) ? dinv[node0 + t + 512] : 0.f;
    __syncthreads();

    for (unsigned i = beg + t; i < end; i += 512)
        atomicAdd(&lcnt[(tmp[i] >> 17) & 1023], 1u);
    __syncthreads();

    unsigned v0 = lcnt[2 * t], v1 = lcnt[2 * t + 1];
    unsigned sp = v0 + v1;
    ssum[t] = sp;
    __syncthreads();
    for (int off = 1; off < 512; off <<= 1) {
        unsigned u = (t >= off) ? ssum[t - off] : 0;
        __syncthreads();
        ssum[t] += u;
        __syncthreads();
    }
    unsigned exclp = ssum[t] - sp;
    unsigned e0 = beg + exclp, e1 = beg + exclp + v0;
    lfill[2 * t] = e0;
    lfill[2 * t + 1] = e1;
    if (node0 + 2 * t < N)     row_ptr[node0 + 2 * t] = (int)e0;
    if (node0 + 2 * t + 1 < N) row_ptr[node0 + 2 * t + 1] = (int)e1;
    __syncthreads();

    for (unsigned i = beg + t; i < end; i += 512) {
        unsigned pkv = tmp[i];
        unsigned sN = pkv & 0x1ffffu;
        unsigned dl = (pkv >> 17) & 1023u;
        unsigned pos = atomicAdd(&lfill[dl], 1u);
        epack[pos] = make_uint2(sN, __float_as_uint(-dinv[sN] * ldinv[dl]));
    }
}

// ---------------- weight prep ----------------
// W layout: [3][H][Eo].  pair: [H][2Eo] = [W1 | 2*W2].  diff: [H][Eo] = W0 - W2.

__global__ void weff_pair(const float* __restrict__ W, int H, int Eo, float* __restrict__ out) {
    int i = blockIdx.x * blockDim.x + threadIdx.x;
    if (i >= H * 2 * Eo) return;
    int h = i / (2 * Eo), n = i % (2 * Eo);
    out[i] = (n < Eo) ? W[(size_t)H * Eo + h * Eo + n]
                      : 2.f * W[(size_t)2 * H * Eo + h * Eo + (n - Eo)];
}

__global__ void weff_diff(const float* __restrict__ W, int H, int Eo, float* __restrict__ out) {
    int i = blockIdx.x * blockDim.x + threadIdx.x;
    if (i < H * Eo) out[i] = W[i] - W[(size_t)2 * H * Eo + i];
}

// ---------------- MFMA GEMM: C[N x BN](bf16) = relu(A @ B + bias + Vadd) ----------------
// 256 threads = 4 waves, 64 rows/block; wave w owns rows w*16..w*16+15, all BN cols.
// B in LDS transposed [n][k] bf16, XOR-swizzled 16B k-blocks. A staged 32-k/step.
// HEAD: BN=32 epilogue computes logits @ Whead + softmax directly (no C store).

template <int BN, int KTOT, bool AF32, bool HEAD>
__global__ __launch_bounds__(256) void mfma_gemm(
    const void* __restrict__ Av, int Nrows,
    const float* __restrict__ B, const float* __restrict__ bias,
    const unsigned short* __restrict__ Vadd,
    unsigned short* __restrict__ C, int do_relu,
    const float* __restrict__ Whead, const float* __restrict__ bhead,
    float* __restrict__ outp)
{
    constexpr int KSTEPS = KTOT / 32;
    constexpr int NT = BN / 16;

    __shared__ unsigned short Bs[BN][KTOT];
    __shared__ unsigned short As[64][56];

    const int tid = threadIdx.x;
    const int w = tid >> 6;
    const int l = tid & 63;
    const int lr = l & 15;
    const int g  = l >> 4;
    const int row0 = blockIdx.x * 64;

    for (int idx = tid; idx < (KTOT / 2) * BN; idx += 256) {
        int n = idx % BN, k = (idx / BN) * 2;
        float w0 = B[(size_t)k * BN + n];
        float w1 = B[(size_t)(k + 1) * BN + n];
        unsigned pk = (unsigned)f2bf(w0) | ((unsigned)f2bf(w1) << 16);
        int sw = (k >> 3) ^ (n & 7);
        *reinterpret_cast<unsigned*>(&Bs[n][sw * 8 + (k & 7)]) = pk;
    }

    float biasv[NT];
#pragma unroll
    for (int t = 0; t < NT; t++) biasv[t] = bias ? bias[t * 16 + lr] : 0.f;

    f32x4 acc[NT];
#pragma unroll
    for (int t = 0; t < NT; t++) acc[t] = (f32x4){0.f, 0.f, 0.f, 0.f};

    const int arow = tid >> 2;
    const int aq = tid & 3;
    const int grow_a = row0 + arow;
    uint4 areg;

    auto loadA = [&](int ks) {
        int kloc = ks * 32 + aq * 8;
        uint4 v = make_uint4(0u, 0u, 0u, 0u);
        if (grow_a < Nrows) {
            if constexpr (AF32) {
                const float* p = (const float*)Av + (size_t)grow_a * KTOT + kloc;
                float4 a0 = *reinterpret_cast<const float4*>(p);
                float4 a1 = *reinterpret_cast<const float4*>(p + 4);
                v.x = (unsigned)f2bf(a0.x) | ((unsigned)f2bf(a0.y) << 16);
                v.y = (unsigned)f2bf(a0.z) | ((unsigned)f2bf(a0.w) << 16);
                v.z = (unsigned)f2bf(a1.x) | ((unsigned)f2bf(a1.y) << 16);
                v.w = (unsigned)f2bf(a1.z) | ((unsigned)f2bf(a1.w) << 16);
            } else {
                v = *reinterpret_cast<const uint4*>((const unsigned short*)Av +
                                                    (size_t)grow_a * KTOT + kloc);
            }
        }
        areg = v;
    };

    loadA(0);
    __syncthreads();   // B staged

    for (int ks = 0; ks < KSTEPS; ks++) {
        *reinterpret_cast<uint4*>(&As[arow][aq * 8]) = areg;
        __syncthreads();
        if (ks + 1 < KSTEPS) loadA(ks + 1);

        bf16x8 af = *reinterpret_cast<const bf16x8*>(&As[w * 16 + lr][g * 8]);
#pragma unroll
        for (int t = 0; t < NT; t++) {
            int sw = ((ks * 4 + g) ^ (lr & 7));
            bf16x8 bf = *reinterpret_cast<const bf16x8*>(&Bs[t * 16 + lr][sw * 8]);
            acc[t] = __builtin_amdgcn_mfma_f32_16x16x32_bf16(af, bf, acc[t], 0, 0, 0);
        }
        __syncthreads();
    }

    if constexpr (HEAD) {
        float wc0[NT], wc1[NT];
#pragma unroll
        for (int t = 0; t < NT; t++) {
            wc0[t] = Whead[(t * 16 + lr) * 2 + 0];
            wc1[t] = Whead[(t * 16 + lr) * 2 + 1];
        }
#pragma unroll
        for (int r = 0; r < 4; r++) {
            int grow = row0 + w * 16 + g * 4 + r;
            bool ok = grow < Nrows;
            float p0 = 0.f, p1 = 0.f;
#pragma unroll
            for (int t = 0; t < NT; t++) {
                float v = acc[t][r] + biasv[t];
                if (ok && Vadd) v += bf2f(Vadd[(size_t)grow * BN + t * 16 + lr]);
                if (do_relu) v = fmaxf(v, 0.f);
                p0 += v * wc0[t];
                p1 += v * wc1[t];
            }
#pragma unroll
            for (int off = 8; off >= 1; off >>= 1) {
                p0 += __shfl_xor(p0, off, 16);
                p1 += __shfl_xor(p1, off, 16);
            }
            if (ok && lr == 0) {
                p0 += bhead[0]; p1 += bhead[1];
                float m = fmaxf(p0, p1);
                float e0 = expf(p0 - m), e1 = expf(p1 - m);
                float s = e0 + e1;
                outp[(size_t)grow * 2 + 0] = e0 / s;
                outp[(size_t)grow * 2 + 1] = e1 / s;
            }
        }
    } else {
#pragma unroll
        for (int t = 0; t < NT; t++) {
#pragma unroll
            for (int r = 0; r < 4; r++) {
                int grow = row0 + w * 16 + g * 4 + r;
                if (grow < Nrows) {
                    float v = acc[t][r] + biasv[t];
                    if (Vadd) v += bf2f(Vadd[(size_t)grow * BN + t * 16 + lr]);
                    if (do_relu) v = fmaxf(v, 0.f);
                    C[(size_t)grow * BN + t * 16 + lr] = f2bf(v);
                }
            }
        }
    }
}

// ---------------- propagation: out[d] = (ADD? adds[d]:0) + sum_e norm_e * h[src_e] ----------
// One node per wave; SLOTS edge-slots x LANES feature-lanes; fp32 accumulate, bf16 out.

template <int F, bool ADD>
__global__ __launch_bounds__(256) void prop_kernel(
    const unsigned short* __restrict__ h, int hstride, int hoff,
    const unsigned short* __restrict__ adds, int astride, int aoff,
    const int* __restrict__ row_ptr, const uint2* __restrict__ epack,
    unsigned short* __restrict__ out, int Nn)
{
    constexpr int LANES = F / 2;       // feature pairs per row
    constexpr int SLOTS = 64 / LANES;  // parallel edge slots per wave
    int node = blockIdx.x * 4 + (threadIdx.x >> 6);
    if (node >= Nn) return;
    int lane = threadIdx.x & 63;
    int fl = (lane % LANES) * 2;
    int slot = lane / LANES;
    int beg = row_ptr[node], end = row_ptr[node + 1];
    const unsigned short* hp = h + hoff + fl;

    float ax = 0.f, ay = 0.f;
    int i = beg + slot;
    for (; i + SLOTS < end; i += 2 * SLOTS) {
        uint2 e0 = epack[i];
        uint2 e1 = epack[i + SLOTS];
        unsigned u0 = *reinterpret_cast<const unsigned*>(&hp[(size_t)e0.x * hstride]);
        unsigned u1 = *reinterpret_cast<const unsigned*>(&hp[(size_t)e1.x * hstride]);
        float w0 = __uint_as_float(e0.y), w1 = __uint_as_float(e1.y);
        ax += __uint_as_float(u0 << 16) * w0 + __uint_as_float(u1 << 16) * w1;
        ay += __uint_as_float(u0 & 0xffff0000u) * w0 + __uint_as_float(u1 & 0xffff0000u) * w1;
    }
    if (i < end) {
        uint2 e0 = epack[i];
        unsigned u0 = *reinterpret_cast<const unsigned*>(&hp[(size_t)e0.x * hstride]);
        float w0 = __uint_as_float(e0.y);
        ax += __uint_as_float(u0 << 16) * w0;
        ay += __uint_as_float(u0 & 0xffff0000u) * w0;
    }
    if (SLOTS >= 4) { ax += __shfl_xor(ax, 16); ay += __shfl_xor(ay, 16); }
    ax += __shfl_xor(ax, 32); ay += __shfl_xor(ay, 32);

    if (lane < LANES) {
        if (ADD) {
            unsigned ua = *reinterpret_cast<const unsigned*>(
                &adds[(size_t)node * astride + aoff + fl]);
            ax += __uint_as_float(ua << 16);
            ay += __uint_as_float(ua & 0xffff0000u);
        }
        unsigned o = (unsigned)f2bf(ax) | ((unsigned)f2bf(ay) << 16);
        *reinterpret_cast<unsigned*>(&out[(size_t)node * F + fl]) = o;
    }
}

// ---------------- launch ----------------

extern "C" void kernel_launch(void* const* d_in, const int* in_sizes, int n_in,
                              void* d_out, int out_size, void* d_ws, size_t ws_size,
                              hipStream_t stream) {
    const float* x       = (const float*)d_in[0];
    const int*   eidx    = (const int*)d_in[1];
    const float* W_lin1  = (const float*)d_in[2];
    const float* b_lin1  = (const float*)d_in[3];
    const float* W_cheb1 = (const float*)d_in[4];
    const float* b_cheb1 = (const float*)d_in[5];
    const float* W_cheb2 = (const float*)d_in[6];
    const float* b_cheb2 = (const float*)d_in[7];
    const float* W_lin2  = (const float*)d_in[8];
    const float* b_lin2  = (const float*)d_in[9];
    float* out = (float*)d_out;

    const int N = in_sizes[0] / IN_DIM;
    const int E = in_sizes[1] / 2;
    const int* src = eidx;
    const int* dst = eidx + E;
    const int nb = (N + 1023) >> 10;   // 98
    const int R  = (N + 16383) >> 14;  // 7

    char* base = (char*)d_ws;
    auto alloc = [&](size_t bytes) -> char* {
        char* p = base;
        base += (bytes + 255) & ~(size_t)255;
        return p;
    };
    unsigned short* h0  = (unsigned short*)alloc((size_t)N * HID * 2);
    unsigned short* Y12 = (unsigned short*)alloc((size_t)N * 2 * EMB1 * 2);
    unsigned short* U1  = (unsigned short*)alloc((size_t)N * EMB1 * 2);
    unsigned short* V1  = (unsigned short*)alloc((size_t)N * EMB1 * 2);
    unsigned short* h1  = (unsigned short*)alloc((size_t)N * EMB1 * 2);
    unsigned short* Z12 = (unsigned short*)alloc((size_t)N * 2 * EMB2 * 2);
    unsigned short* U2  = (unsigned short*)alloc((size_t)N * EMB2 * 2);
    unsigned short* V2  = (unsigned short*)alloc((size_t)N * EMB2 * 2);
    float* dinv  = (float*)alloc((size_t)N * 4);
    uint2* epack = (uint2*)alloc((size_t)E * 8);
    unsigned* tmp     = (unsigned*)alloc((size_t)E * 4);
    unsigned* partial = (unsigned*)alloc((size_t)R * 128 * 8192 * 4);
    int* row_ptr      = (int*)alloc((size_t)(N + 1) * 4);
    unsigned* bucket_cnt  = (unsigned*)alloc(128 * 16 * 4);
    unsigned* bucket_base = (unsigned*)alloc(129 * 4);
    unsigned* bucket_fill = (unsigned*)alloc(128 * 16 * 4);
    float* Wp1 = (float*)alloc((size_t)HID * 2 * EMB1 * 4);
    float* Wd1 = (float*)alloc((size_t)HID * EMB1 * 4);
    float* Wp2 = (float*)alloc((size_t)EMB1 * 2 * EMB2 * 4);
    float* Wd2 = (float*)alloc((size_t)EMB1 * EMB2 * 4);

    hipMemsetAsync(bucket_cnt, 0, 128 * 16 * 4, stream);

    const int EB = (E + 4095) / 4096;  // 391
    bucket_hist<<<EB, 256, 0, stream>>>(dst, E, bucket_cnt);
    bucket_scan<<<1, 128, 0, stream>>>(bucket_cnt, nb, bucket_base, bucket_fill, row_ptr, N, E);
    bucket_scatter<<<EB, 256, 0, stream>>>(src, dst, E, bucket_fill, tmp);
    deg_count<<<R * 128, 256, 0, stream>>>(src, E, partial);
    deg_reduce<<<(N + 255) / 256, 256, 0, stream>>>(partial, dinv, N);
    bucket_sort<<<nb, 512, 0, stream>>>(tmp, bucket_base, dinv, row_ptr, epack, N);

    const int tb = 256;
    weff_pair<<<(HID * 2 * EMB1 + tb - 1) / tb, tb, 0, stream>>>(W_cheb1, HID, EMB1, Wp1);
    weff_diff<<<(HID * EMB1 + tb - 1) / tb, tb, 0, stream>>>(W_cheb1, HID, EMB1, Wd1);
    weff_pair<<<(EMB1 * 2 * EMB2 + tb - 1) / tb, tb, 0, stream>>>(W_cheb2, EMB1, EMB2, Wp2);
    weff_diff<<<(EMB1 * EMB2 + tb - 1) / tb, tb, 0, stream>>>(W_cheb2, EMB1, EMB2, Wd2);

    const int ggrid = (N + 63) / 64;
    const int pgrid = (N + 3) / 4;

    // h0 = relu(x @ W_lin1 + b)
    mfma_gemm<HID, IN_DIM, true, false><<<ggrid, 256, 0, stream>>>(
        x, N, W_lin1, b_lin1, nullptr, h0, 1, nullptr, nullptr, nullptr);
    // Y12 = h0 @ [W1 | 2W2]   (cols 0..63 = Y1, 64..127 = Y2)
    mfma_gemm<2 * EMB1, HID, false, false><<<ggrid, 256, 0, stream>>>(
        h0, N, Wp1, nullptr, nullptr, Y12, 0, nullptr, nullptr, nullptr);
    // U1 = Y1 + S Y2 ; V1 = S U1
    prop_kernel<EMB1, true><<<pgrid, 256, 0, stream>>>(
        Y12, 2 * EMB1, EMB1, Y12, 2 * EMB1, 0, row_ptr, epack, U1, N);
    prop_kernel<EMB1, false><<<pgrid, 256, 0, stream>>>(
        U1, EMB1, 0, nullptr, 0, 0, row_ptr, epack, V1, N);
    // h1 = relu(h0 @ (W0-W2) + V1 + b)
    mfma_gemm<EMB1, HID, false, false><<<ggrid, 256, 0, stream>>>(
        h0, N, Wd1, b_cheb1, V1, h1, 1, nullptr, nullptr, nullptr);
    // Z12 = h1 @ [W1 | 2W2]
    mfma_gemm<2 * EMB2, EMB1, false, false><<<ggrid, 256, 0, stream>>>(
        h1, N, Wp2, nullptr, nullptr, Z12, 0, nullptr, nullptr, nullptr);
    // U2 = Z1 + S Z2 ; V2 = S U2
    prop_kernel<EMB2, true><<<pgrid, 256, 0, stream>>>(
        Z12, 2 * EMB2, EMB2, Z12, 2 * EMB2, 0, row_ptr, epack, U2, N);
    prop_kernel<EMB2, false><<<pgrid, 256, 0, stream>>>(
        U2, EMB2, 0, nullptr, 0, 0, row_ptr, epack, V2, N);
    // fused: h2 = relu(h1 @ (W0-W2) + V2 + b); out = softmax(h2 @ W_lin2 + b_lin2)
    mfma_gemm<EMB2, EMB1, false, true><<<ggrid, 256, 0, stream>>>(
        h1, N, Wd2, b_cheb2, V2, nullptr, 1, W_lin2, b_lin2, out);
}

// Round 6
// 569.478 us; speedup vs baseline: 1.7563x; 1.0636x over previous
//
#include <hip/hip_runtime.h>

// ChebGCN: x -> relu(lin1) -> relu(cheb1) -> relu(cheb2) -> lin2 -> softmax
// N=100000, E=1600000, IN=256, HID=128, EMB1=64, EMB2=32, K=3
// Round 6: B pre-converted to bf16 MFMA-fragment layout in global (L2-broadcast),
// GEMM keeps only a 10KB double-buffered A tile in LDS (conflict-free, 1 barrier/step).

constexpr int IN_DIM = 256;
constexpr int HID    = 128;
constexpr int EMB1   = 64;
constexpr int EMB2   = 32;

typedef __attribute__((ext_vector_type(8))) short bf16x8;
typedef __attribute__((ext_vector_type(4))) float f32x4;

__device__ __forceinline__ float bf2f(unsigned short u) {
    return __uint_as_float((unsigned)u << 16);
}
__device__ __forceinline__ unsigned short f2bf(float f) {
    unsigned u = __float_as_uint(f);
    u += 0x7fffu + ((u >> 16) & 1u);   // RNE
    return (unsigned short)(u >> 16);
}

// ---------------- CSR build: two-level bucket sort by dst ----------------

__global__ __launch_bounds__(256) void bucket_hist(const int* __restrict__ dst, int E,
                                                   unsigned* __restrict__ bucket_cnt) {
    __shared__ unsigned h[128];
    for (int i = threadIdx.x; i < 128; i += 256) h[i] = 0;
    __syncthreads();
    int i0 = blockIdx.x * 4096;
#pragma unroll
    for (int j = 0; j < 16; j++) {
        int i = i0 + j * 256 + threadIdx.x;
        if (i < E) atomicAdd(&h[dst[i] >> 10], 1u);
    }
    __syncthreads();
    for (int i = threadIdx.x; i < 128; i += 256)
        if (h[i]) atomicAdd(&bucket_cnt[i * 16], h[i]);
}

__global__ void bucket_scan(const unsigned* __restrict__ bucket_cnt, int nb,
                            unsigned* __restrict__ bucket_base, unsigned* __restrict__ bucket_fill,
                            int* __restrict__ row_ptr, int N, int E) {
    __shared__ unsigned s[128];
    int t = threadIdx.x;
    unsigned v = (t < nb) ? bucket_cnt[t * 16] : 0;
    s[t] = v;
    __syncthreads();
    for (int off = 1; off < 128; off <<= 1) {
        unsigned u = (t >= off) ? s[t - off] : 0;
        __syncthreads();
        s[t] += u;
        __syncthreads();
    }
    if (t < nb) {
        unsigned excl = s[t] - v;
        bucket_base[t] = excl;
        bucket_fill[t * 16] = excl;
    }
    if (t == nb) bucket_base[nb] = (unsigned)E;
    if (t == 0) row_ptr[N] = E;
}

__global__ __launch_bounds__(256) void bucket_scatter(const int* __restrict__ src,
                                                      const int* __restrict__ dst, int E,
                                                      unsigned* __restrict__ bucket_fill,
                                                      unsigned* __restrict__ tmp) {
    __shared__ unsigned h[128];
    __shared__ unsigned base[128];
    for (int i = threadIdx.x; i < 128; i += 256) h[i] = 0;
    __syncthreads();
    int i0 = blockIdx.x * 4096;
    unsigned pk[16], bk[16];
#pragma unroll
    for (int j = 0; j < 16; j++) {
        int i = i0 + j * 256 + threadIdx.x;
        if (i < E) {
            int sv = src[i], dv = dst[i];
            bk[j] = (unsigned)(dv >> 10);
            pk[j] = (unsigned)sv | ((unsigned)(dv & 1023) << 17);
            atomicAdd(&h[bk[j]], 1u);
        } else {
            bk[j] = 0xffffffffu;
        }
    }
    __syncthreads();
    for (int i = threadIdx.x; i < 128; i += 256)
        base[i] = h[i] ? atomicAdd(&bucket_fill[i * 16], h[i]) : 0u;
    __syncthreads();
    for (int i = threadIdx.x; i < 128; i += 256) h[i] = 0;
    __syncthreads();
#pragma unroll
    for (int j = 0; j < 16; j++) {
        if (bk[j] != 0xffffffffu) {
            unsigned r = atomicAdd(&h[bk[j]], 1u);
            tmp[base[bk[j]] + r] = pk[j];
        }
    }
}

// src out-degree: R ranges x C=64 chunks; 16384 counters packed 2-per-u32 (32KB LDS)
__global__ __launch_bounds__(256) void deg_count(const int* __restrict__ src, int E,
                                                 unsigned* __restrict__ partial) {
    __shared__ unsigned h[8192];
    int r = blockIdx.x >> 6, c = blockIdx.x & 63;
    for (int i = threadIdx.x; i < 8192; i += 256) h[i] = 0;
    __syncthreads();
    int lo = r << 14;
    int per = (E + 63) >> 6;
    int b0 = c * per, b1 = min(b0 + per, E);
    for (int i = b0 + threadIdx.x; i < b1; i += 256) {
        int s = src[i] - lo;
        if ((unsigned)s < 16384u)
            atomicAdd(&h[s >> 1], (s & 1) ? 0x10000u : 1u);
    }
    __syncthreads();
    unsigned* out = partial + ((size_t)blockIdx.x << 13);
    for (int i = threadIdx.x; i < 8192; i += 256) out[i] = h[i];
}

__global__ void deg_reduce(const unsigned* __restrict__ partial, float* __restrict__ dinv, int N) {
    int n = blockIdx.x * 256 + threadIdx.x;
    if (n >= N) return;
    int r = n >> 14, word = (n & 16383) >> 1;
    const unsigned* p = partial + (((size_t)r * 64) << 13) + word;
    unsigned d = 0;
#pragma unroll
    for (int c = 0; c < 64; c++) d += p[(size_t)c << 13];
    d = (n & 1) ? (d >> 16) : (d & 0xffffu);
    dinv[n] = d ? rsqrtf((float)d) : 0.f;
}

// per-bucket: count 1024 local dsts, scan -> row_ptr, place edges as (src, norm)
__global__ __launch_bounds__(512) void bucket_sort(const unsigned* __restrict__ tmp,
                                                   const unsigned* __restrict__ bucket_base,
                                                   const float* __restrict__ dinv,
                                                   int* __restrict__ row_ptr,
                                                   uint2* __restrict__ epack, int N) {
    __shared__ unsigned lcnt[1024];
    __shared__ unsigned lfill[1024];
    __shared__ float    ldinv[1024];
    __shared__ unsigned ssum[512];
    int b = blockIdx.x;
    unsigned beg = bucket_base[b], end = bucket_base[b + 1];
    int node0 = b << 10;
    int t = threadIdx.x;

    lcnt[t] = 0; lcnt[t + 512] = 0;
    ldinv[t]       = (node0 + t < N)       ? dinv[node0 + t]       : 0.f;
    ldinv[t + 512] = (node0 + t + 512 < N) ? dinv[node0 + t + 512] : 0.f;
    __syncthreads();

    for (unsigned i = beg + t; i < end; i += 512)
        atomicAdd(&lcnt[(tmp[i] >> 17) & 1023], 1u);
    __syncthreads();

    unsigned v0 = lcnt[2 * t], v1 = lcnt[2 * t + 1];
    unsigned sp = v0 + v1;
    ssum[t] = sp;
    __syncthreads();
    for (int off = 1; off < 512; off <<= 1) {
        unsigned u = (t >= off) ? ssum[t - off] : 0;
        __syncthreads();
        ssum[t] += u;
        __syncthreads();
    }
    unsigned exclp = ssum[t] - sp;
    unsigned e0 = beg + exclp, e1 = beg + exclp + v0;
    lfill[2 * t] = e0;
    lfill[2 * t + 1] = e1;
    if (node0 + 2 * t < N)     row_ptr[node0 + 2 * t] = (int)e0;
    if (node0 + 2 * t + 1 < N) row_ptr[node0 + 2 * t + 1] = (int)e1;
    __syncthreads();

    for (unsigned i = beg + t; i < end; i += 512) {
        unsigned pkv = tmp[i];
        unsigned sN = pkv & 0x1ffffu;
        unsigned dl = (pkv >> 17) & 1023u;
        unsigned pos = atomicAdd(&lfill[dl], 1u);
        epack[pos] = make_uint2(sN, __float_as_uint(-dinv[sN] * ldinv[dl]));
    }
}

// ---------------- weight prep: fp32 W -> bf16 MFMA B-fragment layout ----------------
// flat = ((ks*NT + t)*64 + lane)*8 + j  holds  B[k = ks*32 + (lane>>4)*8 + j][n = t*16 + (lane&15)]
// mode 0: B = W (K x BN). mode 1: B = [W1 | 2*W2] (W: [3][K][Eo], BN=2*Eo).
// mode 2: B = W0 - W2 (BN = Eo).

__global__ void bprep(const float* __restrict__ W, int K, int BN, int Eo, int mode,
                      unsigned short* __restrict__ out) {
    int i = blockIdx.x * 256 + threadIdx.x;
    if (i >= K * BN) return;
    int j = i & 7, l = (i >> 3) & 63, ft = i >> 9;
    int NT = BN >> 4;
    int ks = ft / NT, t = ft - ks * NT;
    int k = ks * 32 + ((l >> 4) << 3) + j;
    int n = (t << 4) + (l & 15);
    float v;
    if (mode == 0)      v = W[(size_t)k * BN + n];
    else if (mode == 1) v = (n < Eo) ? W[((size_t)K + k) * Eo + n]
                                     : 2.f * W[((size_t)2 * K + k) * Eo + (n - Eo)];
    else                v = W[(size_t)k * Eo + n] - W[((size_t)2 * K + k) * Eo + n];
    out[i] = f2bf(v);
}

// ---------------- MFMA GEMM: C[N x BN](bf16) = relu(A @ B + bias + Vadd) ----------------
// 256 threads = 4 waves, 64 rows/block; wave w owns rows w*16..w*16+15, all BN cols.
// B fragments read from global (same addrs all blocks -> L2 broadcast).
// A double-buffered in As[2][64][40] (80B row stride: 16B-aligned, <=2-way banks).

template <int BN, int KTOT, bool AF32, bool HEAD>
__global__ __launch_bounds__(256) void mfma_gemm(
    const void* __restrict__ Av, int Nrows,
    const unsigned short* __restrict__ Bf, const float* __restrict__ bias,
    const unsigned short* __restrict__ Vadd,
    unsigned short* __restrict__ C, int do_relu,
    const float* __restrict__ Whead, const float* __restrict__ bhead,
    float* __restrict__ outp)
{
    constexpr int KSTEPS = KTOT / 32;
    constexpr int NT = BN / 16;

    __shared__ unsigned short As[2][64][40];

    const int tid = threadIdx.x;
    const int w = tid >> 6;
    const int l = tid & 63;
    const int lr = l & 15;
    const int g  = l >> 4;
    const int row0 = blockIdx.x * 64;

    const int arow = tid >> 2;
    const int aq = tid & 3;
    const int grow_a = row0 + arow;
    uint4 areg;

    auto loadA = [&](int ks) {
        int kloc = ks * 32 + aq * 8;
        uint4 v = make_uint4(0u, 0u, 0u, 0u);
        if (grow_a < Nrows) {
            if constexpr (AF32) {
                const float* p = (const float*)Av + (size_t)grow_a * KTOT + kloc;
                float4 a0 = *reinterpret_cast<const float4*>(p);
                float4 a1 = *reinterpret_cast<const float4*>(p + 4);
                v.x = (unsigned)f2bf(a0.x) | ((unsigned)f2bf(a0.y) << 16);
                v.y = (unsigned)f2bf(a0.z) | ((unsigned)f2bf(a0.w) << 16);
                v.z = (unsigned)f2bf(a1.x) | ((unsigned)f2bf(a1.y) << 16);
                v.w = (unsigned)f2bf(a1.z) | ((unsigned)f2bf(a1.w) << 16);
            } else {
                v = *reinterpret_cast<const uint4*>((const unsigned short*)Av +
                                                    (size_t)grow_a * KTOT + kloc);
            }
        }
        areg = v;
    };

    float biasv[NT];
#pragma unroll
    for (int t = 0; t < NT; t++) biasv[t] = bias ? bias[t * 16 + lr] : 0.f;

    f32x4 acc[NT];
#pragma unroll
    for (int t = 0; t < NT; t++) acc[t] = (f32x4){0.f, 0.f, 0.f, 0.f};

    loadA(0);
    *reinterpret_cast<uint4*>(&As[0][arow][aq * 8]) = areg;
    if (KSTEPS > 1) loadA(1);
    __syncthreads();

    for (int ks = 0; ks < KSTEPS; ks++) {
        bf16x8 af = *reinterpret_cast<const bf16x8*>(&As[ks & 1][w * 16 + lr][g * 8]);
        if (ks + 1 < KSTEPS) {
            *reinterpret_cast<uint4*>(&As[(ks + 1) & 1][arow][aq * 8]) = areg;
            if (ks + 2 < KSTEPS) loadA(ks + 2);
        }
        const unsigned short* bp = Bf + ((size_t)(ks * NT) * 64 + l) * 8;
#pragma unroll
        for (int t = 0; t < NT; t++) {
            bf16x8 bf = *reinterpret_cast<const bf16x8*>(bp + t * 512);
            acc[t] = __builtin_amdgcn_mfma_f32_16x16x32_bf16(af, bf, acc[t], 0, 0, 0);
        }
        if (ks + 1 < KSTEPS) __syncthreads();
    }

    if constexpr (HEAD) {
        float wc0[NT], wc1[NT];
#pragma unroll
        for (int t = 0; t < NT; t++) {
            wc0[t] = Whead[(t * 16 + lr) * 2 + 0];
            wc1[t] = Whead[(t * 16 + lr) * 2 + 1];
        }
#pragma unroll
        for (int r = 0; r < 4; r++) {
            int grow = row0 + w * 16 + g * 4 + r;
            bool ok = grow < Nrows;
            float p0 = 0.f, p1 = 0.f;
#pragma unroll
            for (int t = 0; t < NT; t++) {
                float v = acc[t][r] + biasv[t];
                if (ok && Vadd) v += bf2f(Vadd[(size_t)grow * BN + t * 16 + lr]);
                if (do_relu) v = fmaxf(v, 0.f);
                p0 += v * wc0[t];
                p1 += v * wc1[t];
            }
#pragma unroll
            for (int off = 8; off >= 1; off >>= 1) {
                p0 += __shfl_xor(p0, off, 16);
                p1 += __shfl_xor(p1, off, 16);
            }
            if (ok && lr == 0) {
                p0 += bhead[0]; p1 += bhead[1];
                float m = fmaxf(p0, p1);
                float e0 = expf(p0 - m), e1 = expf(p1 - m);
                float s = e0 + e1;
                outp[(size_t)grow * 2 + 0] = e0 / s;
                outp[(size_t)grow * 2 + 1] = e1 / s;
            }
        }
    } else {
#pragma unroll
        for (int t = 0; t < NT; t++) {
#pragma unroll
            for (int r = 0; r < 4; r++) {
                int grow = row0 + w * 16 + g * 4 + r;
                if (grow < Nrows) {
                    float v = acc[t][r] + biasv[t];
                    if (Vadd) v += bf2f(Vadd[(size_t)grow * BN + t * 16 + lr]);
                    if (do_relu) v = fmaxf(v, 0.f);
                    C[(size_t)grow * BN + t * 16 + lr] = f2bf(v);
                }
            }
        }
    }
}

// ---------------- propagation: out[d] = (ADD? adds[d]:0) + sum_e norm_e * h[src_e] ----------

template <int F, bool ADD>
__global__ __launch_bounds__(256) void prop_kernel(
    const unsigned short* __restrict__ h, int hstride, int hoff,
    const unsigned short* __restrict__ adds, int astride, int aoff,
    const int* __restrict__ row_ptr, const uint2* __restrict__ epack,
    unsigned short* __restrict__ out, int Nn)
{
    constexpr int LANES = F / 2;       // feature pairs per row
    constexpr int SLOTS = 64 / LANES;  // parallel edge slots per wave
    int node = blockIdx.x * 4 + (threadIdx.x >> 6);
    if (node >= Nn) return;
    int lane = threadIdx.x & 63;
    int fl = (lane % LANES) * 2;
    int slot = lane / LANES;
    int beg = row_ptr[node], end = row_ptr[node + 1];
    const unsigned short* hp = h + hoff + fl;

    float ax = 0.f, ay = 0.f;
    int i = beg + slot;
    for (; i + SLOTS < end; i += 2 * SLOTS) {
        uint2 e0 = epack[i];
        uint2 e1 = epack[i + SLOTS];
        unsigned u0 = *reinterpret_cast<const unsigned*>(&hp[(size_t)e0.x * hstride]);
        unsigned u1 = *reinterpret_cast<const unsigned*>(&hp[(size_t)e1.x * hstride]);
        float w0 = __uint_as_float(e0.y), w1 = __uint_as_float(e1.y);
        ax += __uint_as_float(u0 << 16) * w0 + __uint_as_float(u1 << 16) * w1;
        ay += __uint_as_float(u0 & 0xffff0000u) * w0 + __uint_as_float(u1 & 0xffff0000u) * w1;
    }
    if (i < end) {
        uint2 e0 = epack[i];
        unsigned u0 = *reinterpret_cast<const unsigned*>(&hp[(size_t)e0.x * hstride]);
        float w0 = __uint_as_float(e0.y);
        ax += __uint_as_float(u0 << 16) * w0;
        ay += __uint_as_float(u0 & 0xffff0000u) * w0;
    }
    if (SLOTS >= 4) { ax += __shfl_xor(ax, 16); ay += __shfl_xor(ay, 16); }
    ax += __shfl_xor(ax, 32); ay += __shfl_xor(ay, 32);

    if (lane < LANES) {
        if (ADD) {
            unsigned ua = *reinterpret_cast<const unsigned*>(
                &adds[(size_t)node * astride + aoff + fl]);
            ax += __uint_as_float(ua << 16);
            ay += __uint_as_float(ua & 0xffff0000u);
        }
        unsigned o = (unsigned)f2bf(ax) | ((unsigned)f2bf(ay) << 16);
        *reinterpret_cast<unsigned*>(&out[(size_t)node * F + fl]) = o;
    }
}

// ---------------- launch ----------------

extern "C" void kernel_launch(void* const* d_in, const int* in_sizes, int n_in,
                              void* d_out, int out_size, void* d_ws, size_t ws_size,
                              hipStream_t stream) {
    const float* x       = (const float*)d_in[0];
    const int*   eidx    = (const int*)d_in[1];
    const float* W_lin1  = (const float*)d_in[2];
    const float* b_lin1  = (const float*)d_in[3];
    const float* W_cheb1 = (const float*)d_in[4];
    const float* b_cheb1 = (const float*)d_in[5];
    const float* W_cheb2 = (const float*)d_in[6];
    const float* b_cheb2 = (const float*)d_in[7];
    const float* W_lin2  = (const float*)d_in[8];
    const float* b_lin2  = (const float*)d_in[9];
    float* out = (float*)d_out;

    const int N = in_sizes[0] / IN_DIM;
    const int E = in_sizes[1] / 2;
    const int* src = eidx;
    const int* dst = eidx + E;
    const int nb = (N + 1023) >> 10;   // 98
    const int R  = (N + 16383) >> 14;  // 7

    char* base = (char*)d_ws;
    auto alloc = [&](size_t bytes) -> char* {
        char* p = base;
        base += (bytes + 255) & ~(size_t)255;
        return p;
    };
    unsigned short* h0  = (unsigned short*)alloc((size_t)N * HID * 2);
    unsigned short* Y12 = (unsigned short*)alloc((size_t)N * 2 * EMB1 * 2);
    unsigned short* U1  = (unsigned short*)alloc((size_t)N * EMB1 * 2);
    unsigned short* V1  = (unsigned short*)alloc((size_t)N * EMB1 * 2);
    unsigned short* h1  = (unsigned short*)alloc((size_t)N * EMB1 * 2);
    unsigned short* Z12 = (unsigned short*)alloc((size_t)N * 2 * EMB2 * 2);
    unsigned short* U2  = (unsigned short*)alloc((size_t)N * EMB2 * 2);
    unsigned short* V2  = (unsigned short*)alloc((size_t)N * EMB2 * 2);
    float* dinv  = (float*)alloc((size_t)N * 4);
    uint2* epack = (uint2*)alloc((size_t)E * 8);
    unsigned* tmp     = (unsigned*)alloc((size_t)E * 4);
    unsigned* partial = (unsigned*)alloc((size_t)R * 64 * 8192 * 4);
    int* row_ptr      = (int*)alloc((size_t)(N + 1) * 4);
    unsigned* bucket_cnt  = (unsigned*)alloc(128 * 16 * 4);
    unsigned* bucket_base = (unsigned*)alloc(129 * 4);
    unsigned* bucket_fill = (unsigned*)alloc(128 * 16 * 4);
    unsigned short* Bf_l1 = (unsigned short*)alloc((size_t)IN_DIM * HID * 2);
    unsigned short* Bf_p1 = (unsigned short*)alloc((size_t)HID * 2 * EMB1 * 2);
    unsigned short* Bf_d1 = (unsigned short*)alloc((size_t)HID * EMB1 * 2);
    unsigned short* Bf_p2 = (unsigned short*)alloc((size_t)EMB1 * 2 * EMB2 * 2);
    unsigned short* Bf_d2 = (unsigned short*)alloc((size_t)EMB1 * EMB2 * 2);

    hipMemsetAsync(bucket_cnt, 0, 128 * 16 * 4, stream);

    const int EB = (E + 4095) / 4096;  // 391
    bucket_hist<<<EB, 256, 0, stream>>>(dst, E, bucket_cnt);
    bucket_scan<<<1, 128, 0, stream>>>(bucket_cnt, nb, bucket_base, bucket_fill, row_ptr, N, E);
    bucket_scatter<<<EB, 256, 0, stream>>>(src, dst, E, bucket_fill, tmp);
    deg_count<<<R * 64, 256, 0, stream>>>(src, E, partial);
    deg_reduce<<<(N + 255) / 256, 256, 0, stream>>>(partial, dinv, N);
    bucket_sort<<<nb, 512, 0, stream>>>(tmp, bucket_base, dinv, row_ptr, epack, N);

    const int tb = 256;
    bprep<<<(IN_DIM * HID + tb - 1) / tb, tb, 0, stream>>>(W_lin1, IN_DIM, HID, 0, 0, Bf_l1);
    bprep<<<(HID * 2 * EMB1 + tb - 1) / tb, tb, 0, stream>>>(W_cheb1, HID, 2 * EMB1, EMB1, 1, Bf_p1);
    bprep<<<(HID * EMB1 + tb - 1) / tb, tb, 0, stream>>>(W_cheb1, HID, EMB1, EMB1, 2, Bf_d1);
    bprep<<<(EMB1 * 2 * EMB2 + tb - 1) / tb, tb, 0, stream>>>(W_cheb2, EMB1, 2 * EMB2, EMB2, 1, Bf_p2);
    bprep<<<(EMB1 * EMB2 + tb - 1) / tb, tb, 0, stream>>>(W_cheb2, EMB1, EMB2, EMB2, 2, Bf_d2);

    const int ggrid = (N + 63) / 64;
    const int pgrid = (N + 3) / 4;

    // h0 = relu(x @ W_lin1 + b)
    mfma_gemm<HID, IN_DIM, true, false><<<ggrid, 256, 0, stream>>>(
        x, N, Bf_l1, b_lin1, nullptr, h0, 1, nullptr, nullptr, nullptr);
    // Y12 = h0 @ [W1 | 2W2]
    mfma_gemm<2 * EMB1, HID, false, false><<<ggrid, 256, 0, stream>>>(
        h0, N, Bf_p1, nullptr, nullptr, Y12, 0, nullptr, nullptr, nullptr);
    // U1 = Y1 + S Y2 ; V1 = S U1
    prop_kernel<EMB1, true><<<pgrid, 256, 0, stream>>>(
        Y12, 2 * EMB1, EMB1, Y12, 2 * EMB1, 0, row_ptr, epack, U1, N);
    prop_kernel<EMB1, false><<<pgrid, 256, 0, stream>>>(
        U1, EMB1, 0, nullptr, 0, 0, row_ptr, epack, V1, N);
    // h1 = relu(h0 @ (W0-W2) + V1 + b)
    mfma_gemm<EMB1, HID, false, false><<<ggrid, 256, 0, stream>>>(
        h0, N, Bf_d1, b_cheb1, V1, h1, 1, nullptr, nullptr, nullptr);
    // Z12 = h1 @ [W1 | 2W2]
    mfma_gemm<2 * EMB2, EMB1, false, false><<<ggrid, 256, 0, stream>>>(
        h1, N, Bf_p2, nullptr, nullptr, Z12, 0, nullptr, nullptr, nullptr);
    // U2 = Z1 + S Z2 ; V2 = S U2
    prop_kernel<EMB2, true><<<pgrid, 256, 0, stream>>>(
        Z12, 2 * EMB2, EMB2, Z12, 2 * EMB2, 0, row_ptr, epack, U2, N);
    prop_kernel<EMB2, false><<<pgrid, 256, 0, stream>>>(
        U2, EMB2, 0, nullptr, 0, 0, row_ptr, epack, V2, N);
    // fused: h2 = relu(h1 @ (W0-W2) + V2 + b); out = softmax(h2 @ W_lin2 + b_lin2)
    mfma_gemm<EMB2, EMB1, false, true><<<ggrid, 256, 0, stream>>>(
        h1, N, Bf_d2, b_cheb2, V2, nullptr, 1, W_lin2, b_lin2, out);
}

// Round 7
// 514.432 us; speedup vs baseline: 1.9443x; 1.1070x over previous
//
#include <hip/hip_runtime.h>

// ChebGCN: x -> relu(lin1) -> relu(cheb1) -> relu(cheb2) -> lin2 -> softmax
// N=100000, E=1600000, IN=256, HID=128, EMB1=64, EMB2=32, K=3
// Round 7: prop with 16B/lane gathers + 8-16 edge slots/wave (4x MLP); merged bprep.

constexpr int IN_DIM = 256;
constexpr int HID    = 128;
constexpr int EMB1   = 64;
constexpr int EMB2   = 32;

typedef __attribute__((ext_vector_type(8))) short bf16x8;
typedef __attribute__((ext_vector_type(4))) float f32x4;

__device__ __forceinline__ float bf2f(unsigned short u) {
    return __uint_as_float((unsigned)u << 16);
}
__device__ __forceinline__ unsigned short f2bf(float f) {
    unsigned u = __float_as_uint(f);
    u += 0x7fffu + ((u >> 16) & 1u);   // RNE
    return (unsigned short)(u >> 16);
}

// ---------------- CSR build: two-level bucket sort by dst ----------------

__global__ __launch_bounds__(256) void bucket_hist(const int* __restrict__ dst, int E,
                                                   unsigned* __restrict__ bucket_cnt) {
    __shared__ unsigned h[128];
    for (int i = threadIdx.x; i < 128; i += 256) h[i] = 0;
    __syncthreads();
    int i0 = blockIdx.x * 4096;
#pragma unroll
    for (int j = 0; j < 16; j++) {
        int i = i0 + j * 256 + threadIdx.x;
        if (i < E) atomicAdd(&h[dst[i] >> 10], 1u);
    }
    __syncthreads();
    for (int i = threadIdx.x; i < 128; i += 256)
        if (h[i]) atomicAdd(&bucket_cnt[i * 16], h[i]);
}

__global__ void bucket_scan(const unsigned* __restrict__ bucket_cnt, int nb,
                            unsigned* __restrict__ bucket_base, unsigned* __restrict__ bucket_fill,
                            int* __restrict__ row_ptr, int N, int E) {
    __shared__ unsigned s[128];
    int t = threadIdx.x;
    unsigned v = (t < nb) ? bucket_cnt[t * 16] : 0;
    s[t] = v;
    __syncthreads();
    for (int off = 1; off < 128; off <<= 1) {
        unsigned u = (t >= off) ? s[t - off] : 0;
        __syncthreads();
        s[t] += u;
        __syncthreads();
    }
    if (t < nb) {
        unsigned excl = s[t] - v;
        bucket_base[t] = excl;
        bucket_fill[t * 16] = excl;
    }
    if (t == nb) bucket_base[nb] = (unsigned)E;
    if (t == 0) row_ptr[N] = E;
}

__global__ __launch_bounds__(256) void bucket_scatter(const int* __restrict__ src,
                                                      const int* __restrict__ dst, int E,
                                                      unsigned* __restrict__ bucket_fill,
                                                      unsigned* __restrict__ tmp) {
    __shared__ unsigned h[128];
    __shared__ unsigned base[128];
    for (int i = threadIdx.x; i < 128; i += 256) h[i] = 0;
    __syncthreads();
    int i0 = blockIdx.x * 4096;
    unsigned pk[16], bk[16];
#pragma unroll
    for (int j = 0; j < 16; j++) {
        int i = i0 + j * 256 + threadIdx.x;
        if (i < E) {
            int sv = src[i], dv = dst[i];
            bk[j] = (unsigned)(dv >> 10);
            pk[j] = (unsigned)sv | ((unsigned)(dv & 1023) << 17);
            atomicAdd(&h[bk[j]], 1u);
        } else {
            bk[j] = 0xffffffffu;
        }
    }
    __syncthreads();
    for (int i = threadIdx.x; i < 128; i += 256)
        base[i] = h[i] ? atomicAdd(&bucket_fill[i * 16], h[i]) : 0u;
    __syncthreads();
    for (int i = threadIdx.x; i < 128; i += 256) h[i] = 0;
    __syncthreads();
#pragma unroll
    for (int j = 0; j < 16; j++) {
        if (bk[j] != 0xffffffffu) {
            unsigned r = atomicAdd(&h[bk[j]], 1u);
            tmp[base[bk[j]] + r] = pk[j];
        }
    }
}

// src out-degree: R ranges x C=64 chunks; 16384 counters packed 2-per-u32 (32KB LDS)
__global__ __launch_bounds__(256) void deg_count(const int* __restrict__ src, int E,
                                                 unsigned* __restrict__ partial) {
    __shared__ unsigned h[8192];
    int r = blockIdx.x >> 6, c = blockIdx.x & 63;
    for (int i = threadIdx.x; i < 8192; i += 256) h[i] = 0;
    __syncthreads();
    int lo = r << 14;
    int per = (E + 63) >> 6;
    int b0 = c * per, b1 = min(b0 + per, E);
    for (int i = b0 + threadIdx.x; i < b1; i += 256) {
        int s = src[i] - lo;
        if ((unsigned)s < 16384u)
            atomicAdd(&h[s >> 1], (s & 1) ? 0x10000u : 1u);
    }
    __syncthreads();
    unsigned* out = partial + ((size_t)blockIdx.x << 13);
    for (int i = threadIdx.x; i < 8192; i += 256) out[i] = h[i];
}

__global__ void deg_reduce(const unsigned* __restrict__ partial, float* __restrict__ dinv, int N) {
    int n = blockIdx.x * 256 + threadIdx.x;
    if (n >= N) return;
    int r = n >> 14, word = (n & 16383) >> 1;
    const unsigned* p = partial + (((size_t)r * 64) << 13) + word;
    unsigned d = 0;
#pragma unroll
    for (int c = 0; c < 64; c++) d += p[(size_t)c << 13];
    d = (n & 1) ? (d >> 16) : (d & 0xffffu);
    dinv[n] = d ? rsqrtf((float)d) : 0.f;
}

// per-bucket: count 1024 local dsts, scan -> row_ptr, place edges as (src, norm)
__global__ __launch_bounds__(512) void bucket_sort(const unsigned* __restrict__ tmp,
                                                   const unsigned* __restrict__ bucket_base,
                                                   const float* __restrict__ dinv,
                                                   int* __restrict__ row_ptr,
                                                   uint2* __restrict__ epack, int N) {
    __shared__ unsigned lcnt[1024];
    __shared__ unsigned lfill[1024];
    __shared__ float    ldinv[1024];
    __shared__ unsigned ssum[512];
    int b = blockIdx.x;
    unsigned beg = bucket_base[b], end = bucket_base[b + 1];
    int node0 = b << 10;
    int t = threadIdx.x;

    lcnt[t] = 0; lcnt[t + 512] = 0;
    ldinv[t]       = (node0 + t < N)       ? dinv[node0 + t]       : 0.f;
    ldinv[t + 512] = (node0 + t + 512 < N) ? dinv[node0 + t + 512] : 0.f;
    __syncthreads();

    for (unsigned i = beg + t; i < end; i += 512)
        atomicAdd(&lcnt[(tmp[i] >> 17) & 1023], 1u);
    __syncthreads();

    unsigned v0 = lcnt[2 * t], v1 = lcnt[2 * t + 1];
    unsigned sp = v0 + v1;
    ssum[t] = sp;
    __syncthreads();
    for (int off = 1; off < 512; off <<= 1) {
        unsigned u = (t >= off) ? ssum[t - off] : 0;
        __syncthreads();
        ssum[t] += u;
        __syncthreads();
    }
    unsigned exclp = ssum[t] - sp;
    unsigned e0 = beg + exclp, e1 = beg + exclp + v0;
    lfill[2 * t] = e0;
    lfill[2 * t + 1] = e1;
    if (node0 + 2 * t < N)     row_ptr[node0 + 2 * t] = (int)e0;
    if (node0 + 2 * t + 1 < N) row_ptr[node0 + 2 * t + 1] = (int)e1;
    __syncthreads();

    for (unsigned i = beg + t; i < end; i += 512) {
        unsigned pkv = tmp[i];
        unsigned sN = pkv & 0x1ffffu;
        unsigned dl = (pkv >> 17) & 1023u;
        unsigned pos = atomicAdd(&lfill[dl], 1u);
        epack[pos] = make_uint2(sN, __float_as_uint(-dinv[sN] * ldinv[dl]));
    }
}

// ---------------- weight prep: fp32 W -> bf16 MFMA B-fragment layout (all 5 in one) ----
// frag flat = ((ks*NT + t)*64 + lane)*8 + j  holds  B[ks*32 + (lane>>4)*8 + j][t*16 + (lane&15)]

__device__ __forceinline__ void bprep_one(const float* __restrict__ W, int K, int BN, int Eo,
                                          int mode, int i, unsigned short* __restrict__ out) {
    int j = i & 7, l = (i >> 3) & 63, ft = i >> 9;
    int NT = BN >> 4;
    int ks = ft / NT, t = ft - ks * NT;
    int k = ks * 32 + ((l >> 4) << 3) + j;
    int n = (t << 4) + (l & 15);
    float v;
    if (mode == 0)      v = W[(size_t)k * BN + n];
    else if (mode == 1) v = (n < Eo) ? W[((size_t)K + k) * Eo + n]
                                     : 2.f * W[((size_t)2 * K + k) * Eo + (n - Eo)];
    else                v = W[(size_t)k * Eo + n] - W[((size_t)2 * K + k) * Eo + n];
    out[i] = f2bf(v);
}

__global__ void bprep_all(const float* __restrict__ W_lin1, const float* __restrict__ W_cheb1,
                          const float* __restrict__ W_cheb2,
                          unsigned short* __restrict__ Bf_l1, unsigned short* __restrict__ Bf_p1,
                          unsigned short* __restrict__ Bf_d1, unsigned short* __restrict__ Bf_p2,
                          unsigned short* __restrict__ Bf_d2) {
    constexpr int S0 = IN_DIM * HID;            // 32768
    constexpr int S1 = S0 + HID * 2 * EMB1;     // +16384
    constexpr int S2 = S1 + HID * EMB1;         // +8192
    constexpr int S3 = S2 + EMB1 * 2 * EMB2;    // +4096
    constexpr int S4 = S3 + EMB1 * EMB2;        // +2048
    int i = blockIdx.x * 256 + threadIdx.x;
    if (i < S0)      bprep_one(W_lin1,  IN_DIM, HID,      0,    0, i,      Bf_l1);
    else if (i < S1) bprep_one(W_cheb1, HID,    2 * EMB1, EMB1, 1, i - S0, Bf_p1);
    else if (i < S2) bprep_one(W_cheb1, HID,    EMB1,     EMB1, 2, i - S1, Bf_d1);
    else if (i < S3) bprep_one(W_cheb2, EMB1,   2 * EMB2, EMB2, 1, i - S2, Bf_p2);
    else if (i < S4) bprep_one(W_cheb2, EMB1,   EMB2,     EMB2, 2, i - S3, Bf_d2);
}

// ---------------- MFMA GEMM: C[N x BN](bf16) = relu(A @ B + bias + Vadd) ----------------
// 256 threads = 4 waves, 64 rows/block; B fragments from global (L2 broadcast);
// A double-buffered in As[2][64][40].

template <int BN, int KTOT, bool AF32, bool HEAD>
__global__ __launch_bounds__(256) void mfma_gemm(
    const void* __restrict__ Av, int Nrows,
    const unsigned short* __restrict__ Bf, const float* __restrict__ bias,
    const unsigned short* __restrict__ Vadd,
    unsigned short* __restrict__ C, int do_relu,
    const float* __restrict__ Whead, const float* __restrict__ bhead,
    float* __restrict__ outp)
{
    constexpr int KSTEPS = KTOT / 32;
    constexpr int NT = BN / 16;

    __shared__ unsigned short As[2][64][40];

    const int tid = threadIdx.x;
    const int w = tid >> 6;
    const int l = tid & 63;
    const int lr = l & 15;
    const int g  = l >> 4;
    const int row0 = blockIdx.x * 64;

    const int arow = tid >> 2;
    const int aq = tid & 3;
    const int grow_a = row0 + arow;
    uint4 areg;

    auto loadA = [&](int ks) {
        int kloc = ks * 32 + aq * 8;
        uint4 v = make_uint4(0u, 0u, 0u, 0u);
        if (grow_a < Nrows) {
            if constexpr (AF32) {
                const float* p = (const float*)Av + (size_t)grow_a * KTOT + kloc;
                float4 a0 = *reinterpret_cast<const float4*>(p);
                float4 a1 = *reinterpret_cast<const float4*>(p + 4);
                v.x = (unsigned)f2bf(a0.x) | ((unsigned)f2bf(a0.y) << 16);
                v.y = (unsigned)f2bf(a0.z) | ((unsigned)f2bf(a0.w) << 16);
                v.z = (unsigned)f2bf(a1.x) | ((unsigned)f2bf(a1.y) << 16);
                v.w = (unsigned)f2bf(a1.z) | ((unsigned)f2bf(a1.w) << 16);
            } else {
                v = *reinterpret_cast<const uint4*>((const unsigned short*)Av +
                                                    (size_t)grow_a * KTOT + kloc);
            }
        }
        areg = v;
    };

    float biasv[NT];
#pragma unroll
    for (int t = 0; t < NT; t++) biasv[t] = bias ? bias[t * 16 + lr] : 0.f;

    f32x4 acc[NT];
#pragma unroll
    for (int t = 0; t < NT; t++) acc[t] = (f32x4){0.f, 0.f, 0.f, 0.f};

    loadA(0);
    *reinterpret_cast<uint4*>(&As[0][arow][aq * 8]) = areg;
    if (KSTEPS > 1) loadA(1);
    __syncthreads();

    for (int ks = 0; ks < KSTEPS; ks++) {
        bf16x8 af = *reinterpret_cast<const bf16x8*>(&As[ks & 1][w * 16 + lr][g * 8]);
        if (ks + 1 < KSTEPS) {
            *reinterpret_cast<uint4*>(&As[(ks + 1) & 1][arow][aq * 8]) = areg;
            if (ks + 2 < KSTEPS) loadA(ks + 2);
        }
        const unsigned short* bp = Bf + ((size_t)(ks * NT) * 64 + l) * 8;
#pragma unroll
        for (int t = 0; t < NT; t++) {
            bf16x8 bf = *reinterpret_cast<const bf16x8*>(bp + t * 512);
            acc[t] = __builtin_amdgcn_mfma_f32_16x16x32_bf16(af, bf, acc[t], 0, 0, 0);
        }
        if (ks + 1 < KSTEPS) __syncthreads();
    }

    if constexpr (HEAD) {
        float wc0[NT], wc1[NT];
#pragma unroll
        for (int t = 0; t < NT; t++) {
            wc0[t] = Whead[(t * 16 + lr) * 2 + 0];
            wc1[t] = Whead[(t * 16 + lr) * 2 + 1];
        }
#pragma unroll
        for (int r = 0; r < 4; r++) {
            int grow = row0 + w * 16 + g * 4 + r;
            bool ok = grow < Nrows;
            float p0 = 0.f, p1 = 0.f;
#pragma unroll
            for (int t = 0; t < NT; t++) {
                float v = acc[t][r] + biasv[t];
                if (ok && Vadd) v += bf2f(Vadd[(size_t)grow * BN + t * 16 + lr]);
                if (do_relu) v = fmaxf(v, 0.f);
                p0 += v * wc0[t];
                p1 += v * wc1[t];
            }
#pragma unroll
            for (int off = 8; off >= 1; off >>= 1) {
                p0 += __shfl_xor(p0, off, 16);
                p1 += __shfl_xor(p1, off, 16);
            }
            if (ok && lr == 0) {
                p0 += bhead[0]; p1 += bhead[1];
                float m = fmaxf(p0, p1);
                float e0 = expf(p0 - m), e1 = expf(p1 - m);
                float s = e0 + e1;
                outp[(size_t)grow * 2 + 0] = e0 / s;
                outp[(size_t)grow * 2 + 1] = e1 / s;
            }
        }
    } else {
#pragma unroll
        for (int t = 0; t < NT; t++) {
#pragma unroll
            for (int r = 0; r < 4; r++) {
                int grow = row0 + w * 16 + g * 4 + r;
                if (grow < Nrows) {
                    float v = acc[t][r] + biasv[t];
                    if (Vadd) v += bf2f(Vadd[(size_t)grow * BN + t * 16 + lr]);
                    if (do_relu) v = fmaxf(v, 0.f);
                    C[(size_t)grow * BN + t * 16 + lr] = f2bf(v);
                }
            }
        }
    }
}

// ---------------- propagation: out[d] = (ADD? adds[d]:0) + sum_e norm_e * h[src_e] ----------
// One node per wave; 16B/lane rows: LANES=F/8 lanes per row, SLOTS=64/LANES edges in parallel.

template <int F, bool ADD>
__global__ __launch_bounds__(256) void prop_kernel(
    const unsigned short* __restrict__ h, int hstride, int hoff,
    const unsigned short* __restrict__ adds, int astride, int aoff,
    const int* __restrict__ row_ptr, const uint2* __restrict__ epack,
    unsigned short* __restrict__ out, int Nn)
{
    constexpr int LANES = F / 8;       // lanes per row (16B = 8 bf16 each)
    constexpr int SLOTS = 64 / LANES;  // parallel edge slots per wave (8 or 16)
    int node = blockIdx.x * 4 + (threadIdx.x >> 6);
    if (node >= Nn) return;
    int lane = threadIdx.x & 63;
    int fl = (lane % LANES) * 8;
    int slot = lane / LANES;
    int beg = row_ptr[node], end = row_ptr[node + 1];
    const unsigned short* hp = h + hoff + fl;

    float acc[8];
#pragma unroll
    for (int q = 0; q < 8; q++) acc[q] = 0.f;

    auto fma8 = [&](uint4 u, float wv) {
        acc[0] += __uint_as_float(u.x << 16) * wv;
        acc[1] += __uint_as_float(u.x & 0xffff0000u) * wv;
        acc[2] += __uint_as_float(u.y << 16) * wv;
        acc[3] += __uint_as_float(u.y & 0xffff0000u) * wv;
        acc[4] += __uint_as_float(u.z << 16) * wv;
        acc[5] += __uint_as_float(u.z & 0xffff0000u) * wv;
        acc[6] += __uint_as_float(u.w << 16) * wv;
        acc[7] += __uint_as_float(u.w & 0xffff0000u) * wv;
    };

    int i = beg + slot;
    for (; i + SLOTS < end; i += 2 * SLOTS) {
        uint2 e0 = epack[i];
        uint2 e1 = epack[i + SLOTS];
        uint4 u0 = *reinterpret_cast<const uint4*>(&hp[(size_t)e0.x * hstride]);
        uint4 u1 = *reinterpret_cast<const uint4*>(&hp[(size_t)e1.x * hstride]);
        fma8(u0, __uint_as_float(e0.y));
        fma8(u1, __uint_as_float(e1.y));
    }
    if (i < end) {
        uint2 e0 = epack[i];
        uint4 u0 = *reinterpret_cast<const uint4*>(&hp[(size_t)e0.x * hstride]);
        fma8(u0, __uint_as_float(e0.y));
    }

#pragma unroll
    for (int off = LANES; off < 64; off <<= 1) {
#pragma unroll
        for (int q = 0; q < 8; q++) acc[q] += __shfl_xor(acc[q], off);
    }

    if (lane < LANES) {
        if (ADD) {
            uint4 ua = *reinterpret_cast<const uint4*>(
                &adds[(size_t)node * astride + aoff + fl]);
            acc[0] += __uint_as_float(ua.x << 16);
            acc[1] += __uint_as_float(ua.x & 0xffff0000u);
            acc[2] += __uint_as_float(ua.y << 16);
            acc[3] += __uint_as_float(ua.y & 0xffff0000u);
            acc[4] += __uint_as_float(ua.z << 16);
            acc[5] += __uint_as_float(ua.z & 0xffff0000u);
            acc[6] += __uint_as_float(ua.w << 16);
            acc[7] += __uint_as_float(ua.w & 0xffff0000u);
        }
        uint4 o;
        o.x = (unsigned)f2bf(acc[0]) | ((unsigned)f2bf(acc[1]) << 16);
        o.y = (unsigned)f2bf(acc[2]) | ((unsigned)f2bf(acc[3]) << 16);
        o.z = (unsigned)f2bf(acc[4]) | ((unsigned)f2bf(acc[5]) << 16);
        o.w = (unsigned)f2bf(acc[6]) | ((unsigned)f2bf(acc[7]) << 16);
        *reinterpret_cast<uint4*>(&out[(size_t)node * F + fl]) = o;
    }
}

// ---------------- launch ----------------

extern "C" void kernel_launch(void* const* d_in, const int* in_sizes, int n_in,
                              void* d_out, int out_size, void* d_ws, size_t ws_size,
                              hipStream_t stream) {
    const float* x       = (const float*)d_in[0];
    const int*   eidx    = (const int*)d_in[1];
    const float* W_lin1  = (const float*)d_in[2];
    const float* b_lin1  = (const float*)d_in[3];
    const float* W_cheb1 = (const float*)d_in[4];
    const float* b_cheb1 = (const float*)d_in[5];
    const float* W_cheb2 = (const float*)d_in[6];
    const float* b_cheb2 = (const float*)d_in[7];
    const float* W_lin2  = (const float*)d_in[8];
    const float* b_lin2  = (const float*)d_in[9];
    float* out = (float*)d_out;

    const int N = in_sizes[0] / IN_DIM;
    const int E = in_sizes[1] / 2;
    const int* src = eidx;
    const int* dst = eidx + E;
    const int nb = (N + 1023) >> 10;   // 98
    const int R  = (N + 16383) >> 14;  // 7

    char* base = (char*)d_ws;
    auto alloc = [&](size_t bytes) -> char* {
        char* p = base;
        base += (bytes + 255) & ~(size_t)255;
        return p;
    };
    unsigned short* h0  = (unsigned short*)alloc((size_t)N * HID * 2);
    unsigned short* Y12 = (unsigned short*)alloc((size_t)N * 2 * EMB1 * 2);
    unsigned short* U1  = (unsigned short*)alloc((size_t)N * EMB1 * 2);
    unsigned short* V1  = (unsigned short*)alloc((size_t)N * EMB1 * 2);
    unsigned short* h1  = (unsigned short*)alloc((size_t)N * EMB1 * 2);
    unsigned short* Z12 = (unsigned short*)alloc((size_t)N * 2 * EMB2 * 2);
    unsigned short* U2  = (unsigned short*)alloc((size_t)N * EMB2 * 2);
    unsigned short* V2  = (unsigned short*)alloc((size_t)N * EMB2 * 2);
    float* dinv  = (float*)alloc((size_t)N * 4);
    uint2* epack = (uint2*)alloc((size_t)E * 8);
    unsigned* tmp     = (unsigned*)alloc((size_t)E * 4);
    unsigned* partial = (unsigned*)alloc((size_t)R * 64 * 8192 * 4);
    int* row_ptr      = (int*)alloc((size_t)(N + 1) * 4);
    unsigned* bucket_cnt  = (unsigned*)alloc(128 * 16 * 4);
    unsigned* bucket_base = (unsigned*)alloc(129 * 4);
    unsigned* bucket_fill = (unsigned*)alloc(128 * 16 * 4);
    unsigned short* Bf_l1 = (unsigned short*)alloc((size_t)IN_DIM * HID * 2);
    unsigned short* Bf_p1 = (unsigned short*)alloc((size_t)HID * 2 * EMB1 * 2);
    unsigned short* Bf_d1 = (unsigned short*)alloc((size_t)HID * EMB1 * 2);
    unsigned short* Bf_p2 = (unsigned short*)alloc((size_t)EMB1 * 2 * EMB2 * 2);
    unsigned short* Bf_d2 = (unsigned short*)alloc((size_t)EMB1 * EMB2 * 2);

    hipMemsetAsync(bucket_cnt, 0, 128 * 16 * 4, stream);

    const int EB = (E + 4095) / 4096;  // 391
    bucket_hist<<<EB, 256, 0, stream>>>(dst, E, bucket_cnt);
    bucket_scan<<<1, 128, 0, stream>>>(bucket_cnt, nb, bucket_base, bucket_fill, row_ptr, N, E);
    bucket_scatter<<<EB, 256, 0, stream>>>(src, dst, E, bucket_fill, tmp);
    deg_count<<<R * 64, 256, 0, stream>>>(src, E, partial);
    deg_reduce<<<(N + 255) / 256, 256, 0, stream>>>(partial, dinv, N);
    bucket_sort<<<nb, 512, 0, stream>>>(tmp, bucket_base, dinv, row_ptr, epack, N);

    constexpr int BPREP_TOTAL = IN_DIM * HID + HID * 2 * EMB1 + HID * EMB1 +
                                EMB1 * 2 * EMB2 + EMB1 * EMB2;
    bprep_all<<<(BPREP_TOTAL + 255) / 256, 256, 0, stream>>>(
        W_lin1, W_cheb1, W_cheb2, Bf_l1, Bf_p1, Bf_d1, Bf_p2, Bf_d2);

    const int ggrid = (N + 63) / 64;
    const int pgrid = (N + 3) / 4;

    // h0 = relu(x @ W_lin1 + b)
    mfma_gemm<HID, IN_DIM, true, false><<<ggrid, 256, 0, stream>>>(
        x, N, Bf_l1, b_lin1, nullptr, h0, 1, nullptr, nullptr, nullptr);
    // Y12 = h0 @ [W1 | 2W2]
    mfma_gemm<2 * EMB1, HID, false, false><<<ggrid, 256, 0, stream>>>(
        h0, N, Bf_p1, nullptr, nullptr, Y12, 0, nullptr, nullptr, nullptr);
    // U1 = Y1 + S Y2 ; V1 = S U1
    prop_kernel<EMB1, true><<<pgrid, 256, 0, stream>>>(
        Y12, 2 * EMB1, EMB1, Y12, 2 * EMB1, 0, row_ptr, epack, U1, N);
    prop_kernel<EMB1, false><<<pgrid, 256, 0, stream>>>(
        U1, EMB1, 0, nullptr, 0, 0, row_ptr, epack, V1, N);
    // h1 = relu(h0 @ (W0-W2) + V1 + b)
    mfma_gemm<EMB1, HID, false, false><<<ggrid, 256, 0, stream>>>(
        h0, N, Bf_d1, b_cheb1, V1, h1, 1, nullptr, nullptr, nullptr);
    // Z12 = h1 @ [W1 | 2W2]
    mfma_gemm<2 * EMB2, EMB1, false, false><<<ggrid, 256, 0, stream>>>(
        h1, N, Bf_p2, nullptr, nullptr, Z12, 0, nullptr, nullptr, nullptr);
    // U2 = Z1 + S Z2 ; V2 = S U2
    prop_kernel<EMB2, true><<<pgrid, 256, 0, stream>>>(
        Z12, 2 * EMB2, EMB2, Z12, 2 * EMB2, 0, row_ptr, epack, U2, N);
    prop_kernel<EMB2, false><<<pgrid, 256, 0, stream>>>(
        U2, EMB2, 0, nullptr, 0, 0, row_ptr, epack, V2, N);
    // fused: h2 = relu(h1 @ (W0-W2) + V2 + b); out = softmax(h2 @ W_lin2 + b_lin2)
    mfma_gemm<EMB2, EMB1, false, true><<<ggrid, 256, 0, stream>>>(
        h1, N, Bf_d2, b_cheb2, V2, nullptr, 1, W_lin2, b_lin2, out);
}